// Round 6
// baseline (381.258 us; speedup 1.0000x reference)
//
#include <hip/hip_runtime.h>
#include <math.h>

#define B_    128
#define L_    64
#define C_    300
#define NH_   300
#define K_    20
#define HID_  150
#define N_    (B_*L_)       // 8192
#define N2_   (2*N_)        // 16384
#define NFEAT_ 44427
#define FSTRIDE_ 44428      // padded row stride (16B-aligned rows for float4 loads)
#define ZB_   256           // split-K blocks for mlp1 (1 per CU)
#define KST_  1389          // ceil(NFEAT/32) k-steps
#define KCB_  6             // ceil(KST/ZB) k-steps per block
#define CP_   320           // padded C for bf16 GEMM (mult of 32)
#define NROWS_ 16448        // 257*64: N2_ + pad rows (staging window reads up to +81)

typedef __attribute__((ext_vector_type(8))) short bf16x8;
typedef __attribute__((ext_vector_type(4))) float f32x4;

__device__ __forceinline__ float fast_tanh(float x){
    float e = __expf(2.0f*x);
    return 1.0f - 2.0f/(e + 1.0f);
}

__device__ __forceinline__ unsigned short f2bf(float x){
    union { float f; unsigned u; } a; a.f = x;
    unsigned r = a.u + 0x7FFFu + ((a.u >> 16) & 1u);   // RNE
    return (unsigned short)(r >> 16);
}

__device__ __forceinline__ float bf2f(unsigned short h){
    union { unsigned u; float f; } a; a.u = ((unsigned)h) << 16;
    return a.f;
}

// async global->LDS DMA, 16B/lane; lds dest must be wave-uniform base (+lane*16)
__device__ __forceinline__ void gld16(const void* g, void* l){
    __builtin_amdgcn_global_load_lds(
        (__attribute__((address_space(1))) void*)(g),
        (__attribute__((address_space(3))) void*)(l),
        16, 0, 0);
}

// counted vmcnt wait (literal immediate) + compiler memory fence
#define WAITV(N) asm volatile("s_waitcnt vmcnt(" #N ")" ::: "memory")
#define MEMFENCE() asm volatile("" ::: "memory")

// ---------------------------------------------------------------- embedding
// S[c, s*N + b*64 + l] = emb[tok(s,b,l), c]   (fp32, for pdim/inf kernels)
__global__ void k_embed(const int* __restrict__ sa, const int* __restrict__ sb,
                        const float* __restrict__ emb, float* __restrict__ S){
    int n = blockIdx.x*256 + threadIdx.x;      // 0..16383
    int s = n >> 13;
    int nl = n & (N_-1);
    int tok = s ? sb[nl] : sa[nl];
    const float* row = emb + (long)tok * C_;
    int c0 = blockIdx.y * 60;
    const float4* r4 = (const float4*)(row + c0);   // 1200B rows + 240B chunks: 16B aligned
    #pragma unroll
    for (int i = 0; i < 15; ++i){
        float4 f = r4[i];
        long c = c0 + i*4;
        S[c*N2_ + n]     = f.x;
        S[(c+1)*N2_ + n] = f.y;
        S[(c+2)*N2_ + n] = f.z;
        S[(c+3)*N2_ + n] = f.w;
    }
}

// ------------------------------------------------- transposed bf16 S: SbfT[n][c]
__global__ void k_embedT(const int* __restrict__ sa, const int* __restrict__ sb,
                         const float* __restrict__ emb, unsigned short* __restrict__ sbfT){
    int w = threadIdx.x >> 6, lane = threadIdx.x & 63;
    for (int i = 0; i < 16; ++i){
        long n = (long)blockIdx.x*64 + w*16 + i;
        if (n >= NROWS_) return;
        bool pad = (n >= N2_);
        int tok = 0;
        if (!pad) tok = (n >= N_) ? sb[n - N_] : sa[n];
        const float4* er = (const float4*)(emb + (long)tok * C_);
        #pragma unroll
        for (int p = 0; p < 2; ++p){
            int c4 = p*64 + lane;            // float4 index, c = 4*c4
            if (c4 >= CP_/4) continue;
            ushort4 v = {0,0,0,0};
            if (!pad && c4 < 75){
                float4 f = er[c4];
                v.x = f2bf(f.x); v.y = f2bf(f.y); v.z = f2bf(f.z); v.w = f2bf(f.w);
            }
            ((ushort4*)(sbfT + n*CP_))[c4] = v;
        }
    }
}

// ------------------------------------------------- bf16 conv weights, [plane][o][c]
__global__ void k_wprep(const float* __restrict__ hw1, const float* __restrict__ hw2,
                        const float* __restrict__ hw3, unsigned short* __restrict__ wbf){
    int idx = blockIdx.x*256 + threadIdx.x;    // < 6*320*320 = 614400
    int p = idx / (CP_*CP_), r = idx % (CP_*CP_);
    int o = r / CP_, c = r % CP_;
    int WS, j; const float* hw;
    if (p == 0){ WS = 1; j = 0; hw = hw1; }
    else if (p < 3){ WS = 2; j = p - 1; hw = hw2; }
    else { WS = 3; j = p - 3; hw = hw3; }
    float v = (o < NH_ && c < C_) ? hw[((long)o*C_ + c)*WS + j] : 0.0f;
    wbf[idx] = f2bf(v);
}

// ------------------------------------------------- holistic conv via MFMA v8
// = v7 (fused widths + XCD-bijective swizzle) + T3/T4 deep pipeline:
//   4-deep LDS ring, prefetch distance 3, counted s_waitcnt vmcnt(N) + raw
//   s_barrier (NO __syncthreads drain). v7 was L2-latency-serialized: loads got
//   one ~100cyc compute phase of hiding vs ~400cyc L2 latency (MfmaUtil 9%,
//   HBM 2%). Now each chunk's loads have 3 compute phases + issue windows.
// Ring slot safety: stage(ch+3) writes slot (ch+3)&3 = (ch-1)&3, last read at
// it ch-1, sealed by the per-iteration barrier. Per-wave load counts/chunk:
// waves 0-2: 4 gld16, wave 3: 3 -> wave-uniform literal vmcnt.
// P reduction buffer unioned into ring slot 0 (last chunk uses slot (NC-1)&3
// in {1,3} for all WS -> no alias). LDS 61440B -> 2 blocks/CU.
__global__ __launch_bounds__(256) void k_hconv8(const unsigned short* __restrict__ sbfT,
        const unsigned short* __restrict__ wbf,
        const float* __restrict__ hb1, const float* __restrict__ hb2,
        const float* __restrict__ hb3, float* __restrict__ apool){
    __shared__ __align__(16) unsigned char RING[4][15360];  // per slot: A 5120 | B 10240
    int i0 = blockIdx.x;                       // 0..1535
    int bid = (i0 & 7)*192 + (i0 >> 3);        // XCD-contiguous work id (1536 = 8*192)
    int wsi = bid % 3;  int rr0 = bid / 3;     // WS = wsi+1
    int nhalf = rr0 & 1; int sbx = rr0 >> 1;   // sbx 0..255
    const int WS = wsi + 1;
    const int Lo = 65 - WS;
    const int NC = 10*WS;                      // k-chunks (j-major, kc-minor); >= 10
    const long pofs = (long)((WS*(WS-1))/2) * (CP_*CP_);  // plane base {0,1,3}
    const float* hb = (WS == 1) ? hb1 : (WS == 2) ? hb2 : hb3;

    int tid = threadIdx.x;
    int w = tid >> 6, lane = tid & 63, col = lane & 15, quad = lane >> 4;
    int s = sbx >> 7, b = sbx & 127;
    long row0 = (long)sbx*64;
    int mt0 = (w>>1)*2;
    int olocb = (w&1)*80 + col;
    int nbase = nhalf*160;
    f32x4 acc[2][5] = {};

    auto stage = [&](int ch, int bi){
        int j = ch/10, kc = ch - 10*j;
        int kbase = kc*32;
        unsigned short* AL = (unsigned short*)RING[bi];
        unsigned short* BL = (unsigned short*)(RING[bi] + 5120);
        #pragma unroll
        for (int q = 0; q < 15; ++q){
            if ((q & 3) != w) continue;        // wave-uniform branch
            int e = q*64 + lane;
            if (q < 5){
                int qc = e/80, rw = e - qc*80;
                gld16(sbfT + (row0 + j + rw)*CP_ + kbase + qc*8, AL + q*64*8);
            } else {
                int eb = e - 320;
                int qc = eb/160, o = eb - qc*160;
                gld16(wbf + pofs + (long)j*(CP_*CP_) + (long)(nbase+o)*CP_ + kbase + qc*8,
                      BL + (q-5)*64*8);
            }
        }
    };

    // prologue: prefetch chunks 0..2 (outstanding/wave: 12 or 9)
    stage(0, 0); stage(1, 1); stage(2, 2);

    for (int ch = 0; ch < NC; ++ch){
        int rem = NC - 1 - ch;                 // chunks staged beyond ch: min(rem,2)
        if (rem >= 2){ if (w == 3) WAITV(6); else WAITV(8); }
        else if (rem == 1){ if (w == 3) WAITV(3); else WAITV(4); }
        else { WAITV(0); }
        __builtin_amdgcn_s_barrier();          // all waves' chunk-ch DMAs complete
        MEMFENCE();                            // no LDS read hoists above the barrier
        if (ch + 3 < NC) stage(ch + 3, (ch + 3) & 3);
        int cur = ch & 3;
        const unsigned short* AL = (const unsigned short*)RING[cur];
        const unsigned short* BL = (const unsigned short*)(RING[cur] + 5120);
        bf16x8 a0 = *(const bf16x8*)&AL[(quad*80 + mt0*16 + col)*8];
        bf16x8 a1 = *(const bf16x8*)&AL[(quad*80 + (mt0+1)*16 + col)*8];
        #pragma unroll
        for (int ni = 0; ni < 5; ++ni){
            bf16x8 bfr = *(const bf16x8*)&BL[(quad*160 + olocb + ni*16)*8];
            acc[0][ni] = __builtin_amdgcn_mfma_f32_16x16x32_bf16(a0, bfr, acc[0][ni], 0,0,0);
            acc[1][ni] = __builtin_amdgcn_mfma_f32_16x16x32_bf16(a1, bfr, acc[1][ni], 0,0,0);
        }
    }

    // epilogue reduction; P aliases RING slot 0 (safe: last chunk slot != 0)
    float* Pf = (float*)RING;                  // [5][160][3]
    float rmax[5], rmin[5], rsum[5];
    #pragma unroll
    for (int ni = 0; ni < 5; ++ni){
        int oloc = olocb + ni*16;
        int o = nbase + oloc;
        float bias = (o < NH_) ? hb[o] : 0.0f;
        float vmax = -1e30f, vmin = 1e30f, vsum = 0.0f;
        #pragma unroll
        for (int mi = 0; mi < 2; ++mi){
            int mt = mt0 + mi;
            #pragma unroll
            for (int r = 0; r < 4; ++r){
                int t = mt*16 + quad*4 + r;
                if (t < Lo){
                    float z = acc[mi][ni][r] + bias;
                    vmax = fmaxf(vmax, z); vmin = fminf(vmin, z);
                    vsum += fast_tanh(z);
                }
            }
        }
        for (int m = 16; m < 64; m <<= 1){
            vmax = fmaxf(vmax, __shfl_xor(vmax, m, 64));
            vmin = fminf(vmin, __shfl_xor(vmin, m, 64));
            vsum += __shfl_xor(vsum, m, 64);
        }
        rmax[ni] = vmax; rmin[ni] = vmin; rsum[ni] = vsum;
        if (w < 2 && quad == 0){
            Pf[(ni*160 + oloc)*3 + 0] = vmax;
            Pf[(ni*160 + oloc)*3 + 1] = vmin;
            Pf[(ni*160 + oloc)*3 + 2] = vsum;
        }
    }
    __syncthreads();
    if (w >= 2 && quad == 0){
        #pragma unroll
        for (int ni = 0; ni < 5; ++ni){
            int oloc = olocb + ni*16;
            int o = nbase + oloc;
            if (o < NH_){
                float vmax = fmaxf(rmax[ni], Pf[(ni*160 + oloc)*3 + 0]);
                float vmin = fminf(rmin[ni], Pf[(ni*160 + oloc)*3 + 1]);
                float vsum = rsum[ni] + Pf[(ni*160 + oloc)*3 + 2];
                long base = ((long)((s*3 + (WS-1))*3)) * (long)(B_*NH_) + (long)b*NH_ + o;
                apool[base]                  = fast_tanh(vmax);
                apool[base + (long)(B_*NH_)] = -fast_tanh(vmin);
                apool[base + 2L*(B_*NH_)]    = vsum / (float)Lo;
            }
        }
    }
}

// ------------------------------------------------- per-dim conv + pooling v2
__global__ __launch_bounds__(256) void k_pdim(const float* __restrict__ S,
    const float* __restrict__ pw1, const float* __restrict__ pb1,
    const float* __restrict__ pw2, const float* __restrict__ pb2,
    const float* __restrict__ pw3, const float* __restrict__ pb3,
    float* __restrict__ ppool){
    long tid = (long)blockIdx.x*256 + threadIdx.x;   // < 1,536,000
    int k = (int)(tid % 20);
    long r = tid / 20;
    int c = (int)(r % 300); r /= 300;
    int b = (int)(r % 128); int s = (int)(r / 128);
    const float* row = S + (long)c*N2_ + (long)s*N_ + b*64;
    int ck = c*20 + k;
    float w10 = pw1[ck];
    float w20 = pw2[ck*2], w21 = pw2[ck*2+1];
    float w30 = pw3[ck*3], w31 = pw3[ck*3+1], w32 = pw3[ck*3+2];
    float bb1 = pb1[ck], bb2 = pb2[ck], bb3 = pb3[ck];

    float x[64];
    const float4* rp = (const float4*)row;
    #pragma unroll
    for (int i = 0; i < 16; ++i){
        float4 v = rp[i];
        x[i*4+0]=v.x; x[i*4+1]=v.y; x[i*4+2]=v.z; x[i*4+3]=v.w;
    }

    float mx1=-1e30f, mn1=1e30f, mx2=-1e30f, mn2=1e30f, mx3=-1e30f, mn3=1e30f;
    #pragma unroll
    for (int t = 0; t < 64; ++t){
        float z1 = fmaf(w10, x[t], bb1);
        mx1 = fmaxf(mx1, z1); mn1 = fminf(mn1, z1);
    }
    #pragma unroll
    for (int t = 0; t < 63; ++t){
        float z2 = fmaf(w21, x[t+1], fmaf(w20, x[t], bb2));
        mx2 = fmaxf(mx2, z2); mn2 = fminf(mn2, z2);
    }
    #pragma unroll
    for (int t = 0; t < 62; ++t){
        float z3 = fmaf(w32, x[t+2], fmaf(w31, x[t+1], fmaf(w30, x[t], bb3)));
        mx3 = fmaxf(mx3, z3); mn3 = fminf(mn3, z3);
    }

    float outs[6] = { fast_tanh(mx1), -fast_tanh(mn1),
                      fast_tanh(mx2), -fast_tanh(mn2),
                      fast_tanh(mx3), -fast_tanh(mn3) };
    long stride_sw = 128L*6000L;
    long off = (long)b*6000 + (long)c*20 + k;
    #pragma unroll
    for (int wsi = 0; wsi < 3; ++wsi)
        #pragma unroll
        for (int pool = 0; pool < 2; ++pool){
            long slot = (long)((s*3+wsi)*2 + pool);
            ppool[slot*stride_sw + off] = outs[wsi*2+pool];
        }
}

// ------------------------------------------------- whole-sentence (inf) pools
__global__ void k_inf(const float* __restrict__ S, float* __restrict__ ainf){
    int sbx = blockIdx.x; int s = sbx >> 7, b = sbx & 127;
    int tid = threadIdx.x;
    long base = (long)s*N_ + b*64;
    float vmax = -1e30f, vnmax = -1e30f, vsum = 0.f;
    for (int idx = tid; idx < C_*64; idx += 256){
        int c = idx >> 6, l = idx & 63;
        float v = S[(long)c*N2_ + base + l];
        vmax = fmaxf(vmax, v);
        vnmax = fmaxf(vnmax, -v);
        vsum += v;
    }
    for (int m = 1; m < 64; m <<= 1){
        vmax  = fmaxf(vmax,  __shfl_xor(vmax, m, 64));
        vnmax = fmaxf(vnmax, __shfl_xor(vnmax, m, 64));
        vsum += __shfl_xor(vsum, m, 64);
    }
    __shared__ float red[3][4];
    int w = tid >> 6;
    if ((tid & 63) == 0){ red[0][w]=vmax; red[1][w]=vnmax; red[2][w]=vsum; }
    __syncthreads();
    if (tid == 0){
        float a = fmaxf(fmaxf(red[0][0],red[0][1]),fmaxf(red[0][2],red[0][3]));
        float nn= fmaxf(fmaxf(red[1][0],red[1][1]),fmaxf(red[1][2],red[1][3]));
        float su= red[2][0]+red[2][1]+red[2][2]+red[2][3];
        ainf[(s*3+0)*128 + b] = a;
        ainf[(s*3+1)*128 + b] = nn;
        ainf[(s*3+2)*128 + b] = su / (float)(C_*64);
    }
}

// ------------------------------------------------- finite-ws pair features
__global__ void k_pairs(const float* __restrict__ apool, float* __restrict__ feat){
    int b = blockIdx.x, p = blockIdx.y, q = blockIdx.z;
    int w1 = q / 3, w2 = q % 3;
    int lane = threadIdx.x;
    const float* x1 = apool + ((long)((0*3 + w1)*3 + p))*(long)(B_*NH_) + (long)b*NH_;
    const float* x2 = apool + ((long)((1*3 + w2)*3 + p))*(long)(B_*NH_) + (long)b*NH_;
    float dot=0, n1=0, n2=0, d2=0;
    long fb = (long)b*FSTRIDE_;
    long vbase = 24 + (long)p*2721 + (long)q*302;
    for (int i = lane; i < NH_; i += 64){
        float a = x1[i], bb = x2[i];
        dot = fmaf(a, bb, dot); n1 = fmaf(a, a, n1); n2 = fmaf(bb, bb, n2);
        float dd = a - bb + 1e-6f;
        d2 = fmaf(dd, dd, d2);
        feat[fb + vbase + 2 + i] = fabsf(a - bb);
    }
    for (int m = 1; m < 64; m <<= 1){
        dot += __shfl_xor(dot, m, 64);
        n1  += __shfl_xor(n1, m, 64);
        n2  += __shfl_xor(n2, m, 64);
        d2  += __shfl_xor(d2, m, 64);
    }
    if (lane == 0){
        float cosv = dot / fmaxf(sqrtf(n1)*sqrtf(n2), 1e-8f);
        float distv = sqrtf(d2);
        feat[fb + vbase + 0] = cosv;
        feat[fb + vbase + 1] = distv;
        if (w1 == w2){
            feat[fb + p*8 + w1*2 + 0] = cosv;
            feat[fb + p*8 + w1*2 + 1] = distv;
        }
    }
}

// ------------------------------------------------- inf features (scalar dims)
__global__ void k_infeat(const float* __restrict__ ainf, float* __restrict__ feat){
    int t = threadIdx.x;
    if (t >= 384) return;
    int b = t & 127, p = t >> 7;
    float x1 = ainf[(0*3+p)*128 + b];
    float x2 = ainf[(1*3+p)*128 + b];
    float cosv = (x1*x2) / fmaxf(fabsf(x1)*fabsf(x2), 1e-8f);
    float distv = fabsf(x1 - x2 + 1e-6f);
    long fb = (long)b*FSTRIDE_;
    feat[fb + p*8 + 6] = cosv;
    feat[fb + p*8 + 7] = distv;
    long vb = 24 + (long)p*2721 + 9L*302;
    feat[fb + vb + 0] = cosv;
    feat[fb + vb + 1] = distv;
    feat[fb + vb + 2] = fabsf(x1 - x2);
}

// ------------------------------------------------- per-dim pair features v2
__global__ __launch_bounds__(256) void k_pdimfeat(const float* __restrict__ ppool,
                                                  float* __restrict__ feat){
    __shared__ float X1[20*305];
    __shared__ float X2[20*305];
    int b = blockIdx.x, pw = blockIdx.y;
    int pool = pw / 3, wsi = pw % 3;
    int tid = threadIdx.x;
    long stride_sw = 128L*6000L;
    const float* x1 = ppool + (long)((0*3+wsi)*2+pool)*stride_sw + (long)b*6000;
    const float* x2 = ppool + (long)((1*3+wsi)*2+pool)*stride_sw + (long)b*6000;
    for (int idx = tid; idx < 6000; idx += 256){
        int c = idx / 20, k = idx - 20*c;      // element (c,k): original x[c*20+k]
        X1[k*305 + c] = x1[idx];
        X2[k*305 + c] = x2[idx];
    }
    __syncthreads();
    int w = tid >> 6, lane = tid & 63;
    for (int k = w; k < 20; k += 4){
        float dot=0, n1=0, n2=0, d2=0;
        long fb = (long)b*FSTRIDE_ + 8187 + (long)pw*6040 + (long)k*302;
        for (int c = lane; c < C_; c += 64){
            float a = X1[k*305 + c], bb = X2[k*305 + c];
            dot = fmaf(a, bb, dot); n1 = fmaf(a, a, n1); n2 = fmaf(bb, bb, n2);
            float dd = a - bb + 1e-6f;
            d2 = fmaf(dd, dd, d2);
            feat[fb + 2 + c] = fabsf(a - bb);
        }
        for (int m = 1; m < 64; m <<= 1){
            dot += __shfl_xor(dot, m, 64);
            n1  += __shfl_xor(n1, m, 64);
            n2  += __shfl_xor(n2, m, 64);
            d2  += __shfl_xor(d2, m, 64);
        }
        if (lane == 0){
            feat[fb + 0] = dot / fmaxf(sqrtf(n1)*sqrtf(n2), 1e-8f);
            feat[fb + 1] = sqrtf(d2);
        }
    }
}

// ------------------------------------------------- MLP layer 1: MFMA split-K v6
__global__ __launch_bounds__(512) void k_mlp1(const float* __restrict__ feat,
        const float* __restrict__ W1, float* __restrict__ hpart){
    __shared__ __align__(16) unsigned short Bh[2][5120];   // 4 k-octets * 160 n * 8
    __shared__ __align__(16) unsigned short Bl[2][5120];
    int tid = threadIdx.x;
    int w = tid >> 6, lane = tid & 63, col = lane & 15, quad = lane >> 4;
    int z = blockIdx.x;
    int t0 = z * KCB_;
    int ns = KST_ - t0; if (ns > KCB_) ns = KCB_;
    long hbase = (long)z * (128*160);
    int mrow = w*16 + col;                       // wave's m-tile row for A-frag

    if (ns <= 0){
        #pragma unroll
        for (int ni = 0; ni < 10; ++ni)
            #pragma unroll
            for (int r = 0; r < 4; ++r)
                hpart[hbase + (long)(w*16 + quad*4 + r)*160 + ni*16 + col] = 0.0f;
        return;
    }

    // B staging assignment: 2560 (k-pair, n) cells, 5 per thread (constant per step)
    int k2a[5], na[5];
    #pragma unroll
    for (int i = 0; i < 5; ++i){
        int p = i*512 + tid;
        k2a[i] = p / 160; na[i] = p - 160*k2a[i];   // k2 in 0..15 (k = 2*k2), n in 0..159
    }

    const float* arow = feat + (long)mrow * FSTRIDE_;
    float af[8];                 // raw A dwords for current/next step
    float bf0[5], bf1[5];        // raw B pair values
    bf16x8 ah, al;               // current A frags
    f32x4 acc[10] = {};

#define LOADA(STEP) do { \
        int ks_ = t0 + (STEP); \
        int kb_ = ks_*32 + quad*8; \
        if (ks_ < 1388){ \
            float4 f0_ = *(const float4*)(arow + kb_); \
            float4 f1_ = *(const float4*)(arow + kb_ + 4); \
            af[0]=f0_.x; af[1]=f0_.y; af[2]=f0_.z; af[3]=f0_.w; \
            af[4]=f1_.x; af[5]=f1_.y; af[6]=f1_.z; af[7]=f1_.w; \
        } else { \
            _Pragma("unroll") \
            for (int j_ = 0; j_ < 8; ++j_){ \
                int k_ = kb_ + j_; \
                af[j_] = (k_ < NFEAT_) ? arow[k_] : 0.0f; \
            } \
        } } while(0)

#define LOADB(STEP) do { \
        int kb_ = (t0 + (STEP))*32; \
        _Pragma("unroll") \
        for (int i_ = 0; i_ < 5; ++i_){ \
            int k_ = kb_ + 2*k2a[i_]; int n_ = na[i_]; \
            bf0[i_] = (k_   < NFEAT_ && n_ < HID_) ? W1[(long)k_*HID_ + n_]     : 0.0f; \
            bf1[i_] = (k_+1 < NFEAT_ && n_ < HID_) ? W1[(long)(k_+1)*HID_ + n_] : 0.0f; \
        } } while(0)

#define CVTA() do { \
        _Pragma("unroll") \
        for (int j_ = 0; j_ < 8; ++j_){ \
            unsigned short h_ = f2bf(af[j_]); \
            unsigned short l_ = f2bf(af[j_] - bf2f(h_)); \
            ah[j_] = (short)h_; al[j_] = (short)l_; \
        } } while(0)

#define WRITEB(BUF) do { \
        _Pragma("unroll") \
        for (int i_ = 0; i_ < 5; ++i_){ \
            int k2_ = k2a[i_]; int n_ = na[i_]; \
            int q_ = k2_ >> 2, off_ = k2_ & 3; \
            unsigned short h0_ = f2bf(bf0[i_]); \
            unsigned short l0_ = f2bf(bf0[i_] - bf2f(h0_)); \
            unsigned short h1_ = f2bf(bf1[i_]); \
            unsigned short l1_ = f2bf(bf1[i_] - bf2f(h1_)); \
            int ui_ = (q_*160 + n_)*4 + off_; \
            ((unsigned*)Bh[BUF])[ui_] = (unsigned)h0_ | ((unsigned)h1_ << 16); \
            ((unsigned*)Bl[BUF])[ui_] = (unsigned)l0_ | ((unsigned)l1_ << 16); \
        } } while(0)

    // prologue: fetch step 0, stage B(0) into buf 0
    LOADB(0);
    LOADA(0);
    WRITEB(0);

    for (int t = 0; t < ns; ++t){
        __syncthreads();                       // B(t) LDS writes visible to all waves
        CVTA();                                // A(t) raw -> frags (waits its vmcnt)
        bool more = (t+1 < ns);
        if (more){ LOADA(t+1); LOADB(t+1); }   // issue next-step global loads early
        int bi = t & 1;
        #pragma unroll
        for (int ni = 0; ni < 10; ++ni){
            bf16x8 bh = *(const bf16x8*)&Bh[bi][(quad*160 + ni*16 + col)*8];
            bf16x8 bl = *(const bf16x8*)&Bl[bi][(quad*160 + ni*16 + col)*8];
            acc[ni] = __builtin_amdgcn_mfma_f32_16x16x32_bf16(ah, bh, acc[ni], 0,0,0);
            acc[ni] = __builtin_amdgcn_mfma_f32_16x16x32_bf16(al, bh, acc[ni], 0,0,0);
            acc[ni] = __builtin_amdgcn_mfma_f32_16x16x32_bf16(ah, bl, acc[ni], 0,0,0);
        }
        if (more) WRITEB((t+1)&1);             // waits B(t+1) vmcnt; other buffer
    }

#undef LOADA
#undef LOADB
#undef CVTA
#undef WRITEB

    #pragma unroll
    for (int ni = 0; ni < 10; ++ni)
        #pragma unroll
        for (int r = 0; r < 4; ++r)
            hpart[hbase + (long)(w*16 + quad*4 + r)*160 + ni*16 + col] = acc[ni][r];
}

// ------------------------------------------------- reduce split-K partials v2
// grid (75, 4): y-chunk sums 64 z's -> 300 blocks. k_final sums the 4 slices.
__global__ void k_red(const float* __restrict__ hpart, float* __restrict__ hpre4){
    int t = blockIdx.x*256 + threadIdx.x;
    if (t >= 128*HID_) return;
    int y = blockIdx.y;
    int b = t / HID_, n = t % HID_;
    float s = 0.0f;
    int z0 = y*64;
    for (int z = z0; z < z0+64; ++z)
        s += hpart[(long)z*(128*160) + (long)b*160 + n];
    hpre4[(long)y*(128*HID_) + t] = s;
}

// ------------------------------------------------- tanh + layer2 + log_softmax
__global__ void k_final(const float* __restrict__ hpre4, const float* __restrict__ b1,
        const float* __restrict__ W2, const float* __restrict__ b2,
        float* __restrict__ out){
    int b = threadIdx.x;
    if (b >= 128) return;
    float z0 = b2[0], z1 = b2[1];
    for (int n = 0; n < HID_; ++n){
        int idx = b*HID_ + n;
        float hp = hpre4[idx] + hpre4[19200 + idx] + hpre4[38400 + idx] + hpre4[57600 + idx];
        float hv = fast_tanh(hp + b1[n]);
        z0 = fmaf(hv, W2[n*2+0], z0);
        z1 = fmaf(hv, W2[n*2+1], z1);
    }
    float m = fmaxf(z0, z1);
    float lse = m + logf(expf(z0-m) + expf(z1-m));
    out[b*2+0] = z0 - lse;
    out[b*2+1] = z1 - lse;
}

extern "C" void kernel_launch(void* const* d_in, const int* in_sizes, int n_in,
                              void* d_out, int out_size, void* d_ws, size_t ws_size,
                              hipStream_t stream){
    const int*   sa  = (const int*)d_in[0];
    const int*   sb  = (const int*)d_in[1];
    const float* emb = (const float*)d_in[2];
    const float* hw1 = (const float*)d_in[3];
    const float* hb1 = (const float*)d_in[4];
    const float* pw1 = (const float*)d_in[5];
    const float* pb1 = (const float*)d_in[6];
    const float* hw2 = (const float*)d_in[7];
    const float* hb2 = (const float*)d_in[8];
    const float* pw2 = (const float*)d_in[9];
    const float* pb2 = (const float*)d_in[10];
    const float* hw3 = (const float*)d_in[11];
    const float* hb3 = (const float*)d_in[12];
    const float* pw3 = (const float*)d_in[13];
    const float* pb3 = (const float*)d_in[14];
    const float* W1  = (const float*)d_in[15];
    const float* b1  = (const float*)d_in[16];
    const float* W2  = (const float*)d_in[17];
    const float* b2  = (const float*)d_in[18];
    float* out = (float*)d_out;

    float* ws    = (float*)d_ws;
    float* S     = ws;                       // 300*16384      = 4,915,200
    float* APOOL = S + 4915200;              // 2*3*3*128*300  =   691,200
    float* AINF  = APOOL + 691200;           // 2*3*128        =       768
    float* PPOOL = AINF + 768;               // 2*3*2*128*6000 = 9,216,000
    float* FEAT  = PPOOL + 9216000;          // 128*44428      = 5,686,784 (padded rows)
    float* HPRE  = FEAT + 5686784;           // 4*128*150      =    76,800
    // time-multiplexed overlays:
    //  - SbfT (16448*320 bf16 = 2,631,680 floats) + Wbf overlay PPOOL until hconv8
    //    finishes (k_pdim then overwrites)
    //  - HPART (256*128*160 = 5,242,880 floats) overlays S..AINF (dead by mlp1)
    unsigned short* SBFT = (unsigned short*)PPOOL;
    unsigned short* WBF  = (unsigned short*)(PPOOL + 2631680);
    float* HPART = ws;

    k_embed<<<dim3(64, 5), 256, 0, stream>>>(sa, sb, emb, S);
    k_embedT<<<257, 256, 0, stream>>>(sa, sb, emb, SBFT);
    k_wprep<<<2400, 256, 0, stream>>>(hw1, hw2, hw3, WBF);
    k_hconv8<<<1536, 256, 0, stream>>>(SBFT, WBF, hb1, hb2, hb3, APOOL);
    k_pdim<<<6000, 256, 0, stream>>>(S, pw1,pb1, pw2,pb2, pw3,pb3, PPOOL);
    k_inf<<<256, 256, 0, stream>>>(S, AINF);
    k_pairs<<<dim3(128,3,9), 64, 0, stream>>>(APOOL, FEAT);
    k_infeat<<<1, 384, 0, stream>>>(AINF, FEAT);
    k_pdimfeat<<<dim3(128, 6), 256, 0, stream>>>(PPOOL, FEAT);
    k_mlp1<<<dim3(ZB_), 512, 0, stream>>>(FEAT, W1, HPART);
    k_red<<<dim3(75, 4), 256, 0, stream>>>(HPART, HPRE);
    k_final<<<1, 128, 0, stream>>>(HPRE, b1, W2, b2, out);
}

// Round 7
// 350.557 us; speedup vs baseline: 1.0876x; 1.0876x over previous
//
#include <hip/hip_runtime.h>
#include <math.h>

#define B_    128
#define L_    64
#define C_    300
#define NH_   300
#define K_    20
#define HID_  150
#define N_    (B_*L_)       // 8192
#define N2_   (2*N_)        // 16384
#define NFEAT_ 44427
#define FSTRIDE_ 44428      // padded row stride (16B-aligned rows for float4 loads)
#define ZB_   256           // split-K blocks for mlp1 (1 per CU)
#define KST_  1389          // ceil(NFEAT/32) k-steps
#define KCB_  6             // ceil(KST/ZB) k-steps per block
#define CP_   320           // padded C for bf16 GEMM (mult of 32)
#define NROWS_ 16448        // 257*64: N2_ + pad rows (staging window reads up to +81)
#define PLSZ_ 102400        // weight plane size = 10*CP_*32

typedef __attribute__((ext_vector_type(8))) short bf16x8;
typedef __attribute__((ext_vector_type(4))) float f32x4;

__device__ __forceinline__ float fast_tanh(float x){
    float e = __expf(2.0f*x);
    return 1.0f - 2.0f/(e + 1.0f);
}

__device__ __forceinline__ unsigned short f2bf(float x){
    union { float f; unsigned u; } a; a.f = x;
    unsigned r = a.u + 0x7FFFu + ((a.u >> 16) & 1u);   // RNE
    return (unsigned short)(r >> 16);
}

__device__ __forceinline__ float bf2f(unsigned short h){
    union { unsigned u; float f; } a; a.u = ((unsigned)h) << 16;
    return a.f;
}

// async global->LDS DMA, 16B/lane; lds dest must be wave-uniform base (+lane*16)
__device__ __forceinline__ void gld16(const void* g, void* l){
    __builtin_amdgcn_global_load_lds(
        (__attribute__((address_space(1))) void*)(g),
        (__attribute__((address_space(3))) void*)(l),
        16, 0, 0);
}

// ---------------------------------------------------------------- embedding
// S[c, s*N + b*64 + l] = emb[tok(s,b,l), c]   (fp32, for pdim/inf kernels)
__global__ void k_embed(const int* __restrict__ sa, const int* __restrict__ sb,
                        const float* __restrict__ emb, float* __restrict__ S){
    int n = blockIdx.x*256 + threadIdx.x;      // 0..16383
    int s = n >> 13;
    int nl = n & (N_-1);
    int tok = s ? sb[nl] : sa[nl];
    const float* row = emb + (long)tok * C_;
    int c0 = blockIdx.y * 60;
    const float4* r4 = (const float4*)(row + c0);   // 1200B rows + 240B chunks: 16B aligned
    #pragma unroll
    for (int i = 0; i < 15; ++i){
        float4 f = r4[i];
        long c = c0 + i*4;
        S[c*N2_ + n]     = f.x;
        S[(c+1)*N2_ + n] = f.y;
        S[(c+2)*N2_ + n] = f.z;
        S[(c+3)*N2_ + n] = f.w;
    }
}

// ------------------------------------------------- K-chunk-major bf16 S
// SbfK[kc][n][32]: element (n, c=kc*32+i) at kc*(NROWS*32) + n*32 + i.
// A chunk's A-tile (80 rows x 64B at fixed kc) is CONTIGUOUS -> coalesced gld16.
__global__ void k_embedT(const int* __restrict__ sa, const int* __restrict__ sb,
                         const float* __restrict__ emb, unsigned short* __restrict__ sbfK){
    int w = threadIdx.x >> 6, lane = threadIdx.x & 63;
    for (int i = 0; i < 16; ++i){
        long n = (long)blockIdx.x*64 + w*16 + i;
        if (n >= NROWS_) return;
        bool pad = (n >= N2_);
        int tok = 0;
        if (!pad) tok = (n >= N_) ? sb[n - N_] : sa[n];
        const float4* er = (const float4*)(emb + (long)tok * C_);
        #pragma unroll
        for (int p = 0; p < 2; ++p){
            int c4 = p*64 + lane;            // float4 index, c = 4*c4
            if (c4 >= CP_/4) continue;
            ushort4 v = {0,0,0,0};
            if (!pad && c4 < 75){
                float4 f = er[c4];
                v.x = f2bf(f.x); v.y = f2bf(f.y); v.z = f2bf(f.z); v.w = f2bf(f.w);
            }
            ((ushort4*)(sbfK + (long)(c4 >> 3)*(NROWS_*32) + n*32))[c4 & 7] = v;
        }
    }
}

// ------------------------------------------------- bf16 conv weights, K-chunk-major
// WBF[plane][kc][o][32]: a chunk's B-slab (160 o x 64B at fixed kc) is contiguous.
__global__ void k_wprep(const float* __restrict__ hw1, const float* __restrict__ hw2,
                        const float* __restrict__ hw3, unsigned short* __restrict__ wbf){
    int idx = blockIdx.x*256 + threadIdx.x;    // < 6*102400 = 614400
    int p = idx / PLSZ_, r = idx % PLSZ_;
    int kc = r / 10240, r2 = r % 10240;
    int o = r2 / 32, ii = r2 % 32;
    int c = kc*32 + ii;
    int WS, j; const float* hw;
    if (p == 0){ WS = 1; j = 0; hw = hw1; }
    else if (p < 3){ WS = 2; j = p - 1; hw = hw2; }
    else { WS = 3; j = p - 3; hw = hw3; }
    float v = (o < NH_ && c < C_) ? hw[((long)o*C_ + c)*WS + j] : 0.0f;
    wbf[idx] = f2bf(v);
}

// ------------------------------------------------- holistic conv via MFMA v9
// = v7 (fused widths, XCD-bijective swizzle, tap-major, double-buffered) with
// COALESCED staging. v5-v8 all bottomed at 85-97us with MfmaUtil ~9% regardless
// of schedule: every gld16 was a 640B-stride gather = 64 cache lines/instr
// (~30M L2 requests total -> VMEM-request-throughput-bound). K-chunk-major
// layouts make each gld16 read 1KB contiguous (16 lines, 4 lanes/line).
// LDS is row-linear [rr][4 slots x 16B]; slot holds octet qc=(slot^(rr>>1))&3
// (pre-swizzled GLOBAL source per lane, linear LDS dest = gld16 requirement;
// same XOR on read -> 2-way bank conflicts = free). Bit-identical math to v7.
__global__ __launch_bounds__(256) void k_hconv9(const unsigned short* __restrict__ sbfK,
        const unsigned short* __restrict__ wbf,
        const float* __restrict__ hb1, const float* __restrict__ hb2,
        const float* __restrict__ hb3, float* __restrict__ apool){
    __shared__ __align__(16) unsigned short ALB[2][320*8];      // 5120 B per buf
    __shared__ __align__(16) unsigned short BLB[2][640*8];      // 10240 B per buf
    __shared__ float P[5][160][3];
    int i0 = blockIdx.x;                       // 0..1535
    int bid = (i0 & 7)*192 + (i0 >> 3);        // XCD-contiguous work id (1536 = 8*192)
    int wsi = bid % 3;  int rr0 = bid / 3;     // WS = wsi+1
    int nhalf = rr0 & 1; int sbx = rr0 >> 1;   // sbx 0..255
    const int WS = wsi + 1;
    const int Lo = 65 - WS;
    const int NC = 10*WS;                      // k-chunks (j-major, kc-minor)
    const int pbase = (WS*(WS-1))/2;           // plane base {0,1,3}
    const float* hb = (WS == 1) ? hb1 : (WS == 2) ? hb2 : hb3;

    int tid = threadIdx.x;
    int w = tid >> 6, lane = tid & 63, col = lane & 15, quad = lane >> 4;
    int s = sbx >> 7, b = sbx & 127;
    long row0 = (long)sbx*64;
    int mt0 = (w>>1)*2;
    int olocb = (w&1)*80 + col;
    int nbase = nhalf*160;
    f32x4 acc[2][5] = {};

    auto stage = [&](int ch, int bi){
        int j = ch/10, kc = ch - 10*j;
        const unsigned short* asrc = sbfK + (long)kc*(NROWS_*32) + (row0 + j)*32;
        const unsigned short* bsrc = wbf + (long)(pbase + j)*PLSZ_
                                         + (long)kc*(CP_*32) + (long)nbase*32;
        #pragma unroll
        for (int q = 0; q < 15; ++q){
            if ((q & 3) != w) continue;        // wave-uniform branch
            int e = q*64 + lane;
            if (q < 5){
                int rr = e >> 2, slot = e & 3;
                int qc = (slot ^ (rr >> 1)) & 3;
                gld16(asrc + rr*32 + qc*8, &ALB[bi][q*64*8]);
            } else {
                int eb = e - 320;              // 0..639
                int o = eb >> 2, slot = eb & 3;
                int qc = (slot ^ (o >> 1)) & 3;
                gld16(bsrc + o*32 + qc*8, &BLB[bi][(q-5)*64*8]);
            }
        }
    };

    stage(0, 0);
    for (int ch = 0; ch < NC; ++ch){
        int cur = ch & 1;
        __syncthreads();                       // drains chunk ch's loads; prior reads done
        if (ch+1 < NC) stage(ch+1, cur^1);
        int ra0 = mt0*16 + col;
        int ra1 = ra0 + 16;
        bf16x8 a0 = *(const bf16x8*)&ALB[cur][(ra0*4 + ((quad ^ (ra0>>1)) & 3))*8];
        bf16x8 a1 = *(const bf16x8*)&ALB[cur][(ra1*4 + ((quad ^ (ra1>>1)) & 3))*8];
        #pragma unroll
        for (int ni = 0; ni < 5; ++ni){
            int o = olocb + ni*16;
            bf16x8 bfr = *(const bf16x8*)&BLB[cur][(o*4 + ((quad ^ (o>>1)) & 3))*8];
            acc[0][ni] = __builtin_amdgcn_mfma_f32_16x16x32_bf16(a0, bfr, acc[0][ni], 0,0,0);
            acc[1][ni] = __builtin_amdgcn_mfma_f32_16x16x32_bf16(a1, bfr, acc[1][ni], 0,0,0);
        }
    }

    float rmax[5], rmin[5], rsum[5];
    #pragma unroll
    for (int ni = 0; ni < 5; ++ni){
        int oloc = olocb + ni*16;
        int o = nbase + oloc;
        float bias = (o < NH_) ? hb[o] : 0.0f;
        float vmax = -1e30f, vmin = 1e30f, vsum = 0.0f;
        #pragma unroll
        for (int mi = 0; mi < 2; ++mi){
            int mt = mt0 + mi;
            #pragma unroll
            for (int r = 0; r < 4; ++r){
                int t = mt*16 + quad*4 + r;
                if (t < Lo){
                    float z = acc[mi][ni][r] + bias;
                    vmax = fmaxf(vmax, z); vmin = fminf(vmin, z);
                    vsum += fast_tanh(z);
                }
            }
        }
        for (int m = 16; m < 64; m <<= 1){
            vmax = fmaxf(vmax, __shfl_xor(vmax, m, 64));
            vmin = fminf(vmin, __shfl_xor(vmin, m, 64));
            vsum += __shfl_xor(vsum, m, 64);
        }
        rmax[ni] = vmax; rmin[ni] = vmin; rsum[ni] = vsum;
        if (w < 2 && quad == 0){
            P[ni][oloc][0] = vmax; P[ni][oloc][1] = vmin; P[ni][oloc][2] = vsum;
        }
    }
    __syncthreads();
    if (w >= 2 && quad == 0){
        #pragma unroll
        for (int ni = 0; ni < 5; ++ni){
            int oloc = olocb + ni*16;
            int o = nbase + oloc;
            if (o < NH_){
                float vmax = fmaxf(rmax[ni], P[ni][oloc][0]);
                float vmin = fminf(rmin[ni], P[ni][oloc][1]);
                float vsum = rsum[ni] + P[ni][oloc][2];
                long base = ((long)((s*3 + (WS-1))*3)) * (long)(B_*NH_) + (long)b*NH_ + o;
                apool[base]                  = fast_tanh(vmax);
                apool[base + (long)(B_*NH_)] = -fast_tanh(vmin);
                apool[base + 2L*(B_*NH_)]    = vsum / (float)Lo;
            }
        }
    }
}

// ------------------------------------------------- per-dim conv + pooling v2
__global__ __launch_bounds__(256) void k_pdim(const float* __restrict__ S,
    const float* __restrict__ pw1, const float* __restrict__ pb1,
    const float* __restrict__ pw2, const float* __restrict__ pb2,
    const float* __restrict__ pw3, const float* __restrict__ pb3,
    float* __restrict__ ppool){
    long tid = (long)blockIdx.x*256 + threadIdx.x;   // < 1,536,000
    int k = (int)(tid % 20);
    long r = tid / 20;
    int c = (int)(r % 300); r /= 300;
    int b = (int)(r % 128); int s = (int)(r / 128);
    const float* row = S + (long)c*N2_ + (long)s*N_ + b*64;
    int ck = c*20 + k;
    float w10 = pw1[ck];
    float w20 = pw2[ck*2], w21 = pw2[ck*2+1];
    float w30 = pw3[ck*3], w31 = pw3[ck*3+1], w32 = pw3[ck*3+2];
    float bb1 = pb1[ck], bb2 = pb2[ck], bb3 = pb3[ck];

    float x[64];
    const float4* rp = (const float4*)row;
    #pragma unroll
    for (int i = 0; i < 16; ++i){
        float4 v = rp[i];
        x[i*4+0]=v.x; x[i*4+1]=v.y; x[i*4+2]=v.z; x[i*4+3]=v.w;
    }

    float mx1=-1e30f, mn1=1e30f, mx2=-1e30f, mn2=1e30f, mx3=-1e30f, mn3=1e30f;
    #pragma unroll
    for (int t = 0; t < 64; ++t){
        float z1 = fmaf(w10, x[t], bb1);
        mx1 = fmaxf(mx1, z1); mn1 = fminf(mn1, z1);
    }
    #pragma unroll
    for (int t = 0; t < 63; ++t){
        float z2 = fmaf(w21, x[t+1], fmaf(w20, x[t], bb2));
        mx2 = fmaxf(mx2, z2); mn2 = fminf(mn2, z2);
    }
    #pragma unroll
    for (int t = 0; t < 62; ++t){
        float z3 = fmaf(w32, x[t+2], fmaf(w31, x[t+1], fmaf(w30, x[t], bb3)));
        mx3 = fmaxf(mx3, z3); mn3 = fminf(mn3, z3);
    }

    float outs[6] = { fast_tanh(mx1), -fast_tanh(mn1),
                      fast_tanh(mx2), -fast_tanh(mn2),
                      fast_tanh(mx3), -fast_tanh(mn3) };
    long stride_sw = 128L*6000L;
    long off = (long)b*6000 + (long)c*20 + k;
    #pragma unroll
    for (int wsi = 0; wsi < 3; ++wsi)
        #pragma unroll
        for (int pool = 0; pool < 2; ++pool){
            long slot = (long)((s*3+wsi)*2 + pool);
            ppool[slot*stride_sw + off] = outs[wsi*2+pool];
        }
}

// ------------------------------------------------- whole-sentence (inf) pools
__global__ void k_inf(const float* __restrict__ S, float* __restrict__ ainf){
    int sbx = blockIdx.x; int s = sbx >> 7, b = sbx & 127;
    int tid = threadIdx.x;
    long base = (long)s*N_ + b*64;
    float vmax = -1e30f, vnmax = -1e30f, vsum = 0.f;
    for (int idx = tid; idx < C_*64; idx += 256){
        int c = idx >> 6, l = idx & 63;
        float v = S[(long)c*N2_ + base + l];
        vmax = fmaxf(vmax, v);
        vnmax = fmaxf(vnmax, -v);
        vsum += v;
    }
    for (int m = 1; m < 64; m <<= 1){
        vmax  = fmaxf(vmax,  __shfl_xor(vmax, m, 64));
        vnmax = fmaxf(vnmax, __shfl_xor(vnmax, m, 64));
        vsum += __shfl_xor(vsum, m, 64);
    }
    __shared__ float red[3][4];
    int w = tid >> 6;
    if ((tid & 63) == 0){ red[0][w]=vmax; red[1][w]=vnmax; red[2][w]=vsum; }
    __syncthreads();
    if (tid == 0){
        float a = fmaxf(fmaxf(red[0][0],red[0][1]),fmaxf(red[0][2],red[0][3]));
        float nn= fmaxf(fmaxf(red[1][0],red[1][1]),fmaxf(red[1][2],red[1][3]));
        float su= red[2][0]+red[2][1]+red[2][2]+red[2][3];
        ainf[(s*3+0)*128 + b] = a;
        ainf[(s*3+1)*128 + b] = nn;
        ainf[(s*3+2)*128 + b] = su / (float)(C_*64);
    }
}

// ------------------------------------------------- finite-ws pair features
__global__ void k_pairs(const float* __restrict__ apool, float* __restrict__ feat){
    int b = blockIdx.x, p = blockIdx.y, q = blockIdx.z;
    int w1 = q / 3, w2 = q % 3;
    int lane = threadIdx.x;
    const float* x1 = apool + ((long)((0*3 + w1)*3 + p))*(long)(B_*NH_) + (long)b*NH_;
    const float* x2 = apool + ((long)((1*3 + w2)*3 + p))*(long)(B_*NH_) + (long)b*NH_;
    float dot=0, n1=0, n2=0, d2=0;
    long fb = (long)b*FSTRIDE_;
    long vbase = 24 + (long)p*2721 + (long)q*302;
    for (int i = lane; i < NH_; i += 64){
        float a = x1[i], bb = x2[i];
        dot = fmaf(a, bb, dot); n1 = fmaf(a, a, n1); n2 = fmaf(bb, bb, n2);
        float dd = a - bb + 1e-6f;
        d2 = fmaf(dd, dd, d2);
        feat[fb + vbase + 2 + i] = fabsf(a - bb);
    }
    for (int m = 1; m < 64; m <<= 1){
        dot += __shfl_xor(dot, m, 64);
        n1  += __shfl_xor(n1, m, 64);
        n2  += __shfl_xor(n2, m, 64);
        d2  += __shfl_xor(d2, m, 64);
    }
    if (lane == 0){
        float cosv = dot / fmaxf(sqrtf(n1)*sqrtf(n2), 1e-8f);
        float distv = sqrtf(d2);
        feat[fb + vbase + 0] = cosv;
        feat[fb + vbase + 1] = distv;
        if (w1 == w2){
            feat[fb + p*8 + w1*2 + 0] = cosv;
            feat[fb + p*8 + w1*2 + 1] = distv;
        }
    }
}

// ------------------------------------------------- inf features (scalar dims)
__global__ void k_infeat(const float* __restrict__ ainf, float* __restrict__ feat){
    int t = threadIdx.x;
    if (t >= 384) return;
    int b = t & 127, p = t >> 7;
    float x1 = ainf[(0*3+p)*128 + b];
    float x2 = ainf[(1*3+p)*128 + b];
    float cosv = (x1*x2) / fmaxf(fabsf(x1)*fabsf(x2), 1e-8f);
    float distv = fabsf(x1 - x2 + 1e-6f);
    long fb = (long)b*FSTRIDE_;
    feat[fb + p*8 + 6] = cosv;
    feat[fb + p*8 + 7] = distv;
    long vb = 24 + (long)p*2721 + 9L*302;
    feat[fb + vb + 0] = cosv;
    feat[fb + vb + 1] = distv;
    feat[fb + vb + 2] = fabsf(x1 - x2);
}

// ------------------------------------------------- per-dim pair features v2
__global__ __launch_bounds__(256) void k_pdimfeat(const float* __restrict__ ppool,
                                                  float* __restrict__ feat){
    __shared__ float X1[20*305];
    __shared__ float X2[20*305];
    int b = blockIdx.x, pw = blockIdx.y;
    int pool = pw / 3, wsi = pw % 3;
    int tid = threadIdx.x;
    long stride_sw = 128L*6000L;
    const float* x1 = ppool + (long)((0*3+wsi)*2+pool)*stride_sw + (long)b*6000;
    const float* x2 = ppool + (long)((1*3+wsi)*2+pool)*stride_sw + (long)b*6000;
    for (int idx = tid; idx < 6000; idx += 256){
        int c = idx / 20, k = idx - 20*c;      // element (c,k): original x[c*20+k]
        X1[k*305 + c] = x1[idx];
        X2[k*305 + c] = x2[idx];
    }
    __syncthreads();
    int w = tid >> 6, lane = tid & 63;
    for (int k = w; k < 20; k += 4){
        float dot=0, n1=0, n2=0, d2=0;
        long fb = (long)b*FSTRIDE_ + 8187 + (long)pw*6040 + (long)k*302;
        for (int c = lane; c < C_; c += 64){
            float a = X1[k*305 + c], bb = X2[k*305 + c];
            dot = fmaf(a, bb, dot); n1 = fmaf(a, a, n1); n2 = fmaf(bb, bb, n2);
            float dd = a - bb + 1e-6f;
            d2 = fmaf(dd, dd, d2);
            feat[fb + 2 + c] = fabsf(a - bb);
        }
        for (int m = 1; m < 64; m <<= 1){
            dot += __shfl_xor(dot, m, 64);
            n1  += __shfl_xor(n1, m, 64);
            n2  += __shfl_xor(n2, m, 64);
            d2  += __shfl_xor(d2, m, 64);
        }
        if (lane == 0){
            feat[fb + 0] = dot / fmaxf(sqrtf(n1)*sqrtf(n2), 1e-8f);
            feat[fb + 1] = sqrtf(d2);
        }
    }
}

// ------------------------------------------------- MLP layer 1: MFMA split-K v6
__global__ __launch_bounds__(512) void k_mlp1(const float* __restrict__ feat,
        const float* __restrict__ W1, float* __restrict__ hpart){
    __shared__ __align__(16) unsigned short Bh[2][5120];   // 4 k-octets * 160 n * 8
    __shared__ __align__(16) unsigned short Bl[2][5120];
    int tid = threadIdx.x;
    int w = tid >> 6, lane = tid & 63, col = lane & 15, quad = lane >> 4;
    int z = blockIdx.x;
    int t0 = z * KCB_;
    int ns = KST_ - t0; if (ns > KCB_) ns = KCB_;
    long hbase = (long)z * (128*160);
    int mrow = w*16 + col;                       // wave's m-tile row for A-frag

    if (ns <= 0){
        #pragma unroll
        for (int ni = 0; ni < 10; ++ni)
            #pragma unroll
            for (int r = 0; r < 4; ++r)
                hpart[hbase + (long)(w*16 + quad*4 + r)*160 + ni*16 + col] = 0.0f;
        return;
    }

    // B staging assignment: 2560 (k-pair, n) cells, 5 per thread (constant per step)
    int k2a[5], na[5];
    #pragma unroll
    for (int i = 0; i < 5; ++i){
        int p = i*512 + tid;
        k2a[i] = p / 160; na[i] = p - 160*k2a[i];   // k2 in 0..15 (k = 2*k2), n in 0..159
    }

    const float* arow = feat + (long)mrow * FSTRIDE_;
    float af[8];                 // raw A dwords for current/next step
    float bf0[5], bf1[5];        // raw B pair values
    bf16x8 ah, al;               // current A frags
    f32x4 acc[10] = {};

#define LOADA(STEP) do { \
        int ks_ = t0 + (STEP); \
        int kb_ = ks_*32 + quad*8; \
        if (ks_ < 1388){ \
            float4 f0_ = *(const float4*)(arow + kb_); \
            float4 f1_ = *(const float4*)(arow + kb_ + 4); \
            af[0]=f0_.x; af[1]=f0_.y; af[2]=f0_.z; af[3]=f0_.w; \
            af[4]=f1_.x; af[5]=f1_.y; af[6]=f1_.z; af[7]=f1_.w; \
        } else { \
            _Pragma("unroll") \
            for (int j_ = 0; j_ < 8; ++j_){ \
                int k_ = kb_ + j_; \
                af[j_] = (k_ < NFEAT_) ? arow[k_] : 0.0f; \
            } \
        } } while(0)

#define LOADB(STEP) do { \
        int kb_ = (t0 + (STEP))*32; \
        _Pragma("unroll") \
        for (int i_ = 0; i_ < 5; ++i_){ \
            int k_ = kb_ + 2*k2a[i_]; int n_ = na[i_]; \
            bf0[i_] = (k_   < NFEAT_ && n_ < HID_) ? W1[(long)k_*HID_ + n_]     : 0.0f; \
            bf1[i_] = (k_+1 < NFEAT_ && n_ < HID_) ? W1[(long)(k_+1)*HID_ + n_] : 0.0f; \
        } } while(0)

#define CVTA() do { \
        _Pragma("unroll") \
        for (int j_ = 0; j_ < 8; ++j_){ \
            unsigned short h_ = f2bf(af[j_]); \
            unsigned short l_ = f2bf(af[j_] - bf2f(h_)); \
            ah[j_] = (short)h_; al[j_] = (short)l_; \
        } } while(0)

#define WRITEB(BUF) do { \
        _Pragma("unroll") \
        for (int i_ = 0; i_ < 5; ++i_){ \
            int k2_ = k2a[i_]; int n_ = na[i_]; \
            int q_ = k2_ >> 2, off_ = k2_ & 3; \
            unsigned short h0_ = f2bf(bf0[i_]); \
            unsigned short l0_ = f2bf(bf0[i_] - bf2f(h0_)); \
            unsigned short h1_ = f2bf(bf1[i_]); \
            unsigned short l1_ = f2bf(bf1[i_] - bf2f(h1_)); \
            int ui_ = (q_*160 + n_)*4 + off_; \
            ((unsigned*)Bh[BUF])[ui_] = (unsigned)h0_ | ((unsigned)h1_ << 16); \
            ((unsigned*)Bl[BUF])[ui_] = (unsigned)l0_ | ((unsigned)l1_ << 16); \
        } } while(0)

    // prologue: fetch step 0, stage B(0) into buf 0
    LOADB(0);
    LOADA(0);
    WRITEB(0);

    for (int t = 0; t < ns; ++t){
        __syncthreads();                       // B(t) LDS writes visible to all waves
        CVTA();                                // A(t) raw -> frags (waits its vmcnt)
        bool more = (t+1 < ns);
        if (more){ LOADA(t+1); LOADB(t+1); }   // issue next-step global loads early
        int bi = t & 1;
        #pragma unroll
        for (int ni = 0; ni < 10; ++ni){
            bf16x8 bh = *(const bf16x8*)&Bh[bi][(quad*160 + ni*16 + col)*8];
            bf16x8 bl = *(const bf16x8*)&Bl[bi][(quad*160 + ni*16 + col)*8];
            acc[ni] = __builtin_amdgcn_mfma_f32_16x16x32_bf16(ah, bh, acc[ni], 0,0,0);
            acc[ni] = __builtin_amdgcn_mfma_f32_16x16x32_bf16(al, bh, acc[ni], 0,0,0);
            acc[ni] = __builtin_amdgcn_mfma_f32_16x16x32_bf16(ah, bl, acc[ni], 0,0,0);
        }
        if (more) WRITEB((t+1)&1);             // waits B(t+1) vmcnt; other buffer
    }

#undef LOADA
#undef LOADB
#undef CVTA
#undef WRITEB

    #pragma unroll
    for (int ni = 0; ni < 10; ++ni)
        #pragma unroll
        for (int r = 0; r < 4; ++r)
            hpart[hbase + (long)(w*16 + quad*4 + r)*160 + ni*16 + col] = acc[ni][r];
}

// ------------------------------------------------- reduce split-K partials v2
// grid (75, 4): y-chunk sums 64 z's -> 300 blocks. k_final sums the 4 slices.
__global__ void k_red(const float* __restrict__ hpart, float* __restrict__ hpre4){
    int t = blockIdx.x*256 + threadIdx.x;
    if (t >= 128*HID_) return;
    int y = blockIdx.y;
    int b = t / HID_, n = t % HID_;
    float s = 0.0f;
    int z0 = y*64;
    for (int z = z0; z < z0+64; ++z)
        s += hpart[(long)z*(128*160) + (long)b*160 + n];
    hpre4[(long)y*(128*HID_) + t] = s;
}

// ------------------------------------------------- tanh + layer2 + log_softmax
__global__ void k_final(const float* __restrict__ hpre4, const float* __restrict__ b1,
        const float* __restrict__ W2, const float* __restrict__ b2,
        float* __restrict__ out){
    int b = threadIdx.x;
    if (b >= 128) return;
    float z0 = b2[0], z1 = b2[1];
    for (int n = 0; n < HID_; ++n){
        int idx = b*HID_ + n;
        float hp = hpre4[idx] + hpre4[19200 + idx] + hpre4[38400 + idx] + hpre4[57600 + idx];
        float hv = fast_tanh(hp + b1[n]);
        z0 = fmaf(hv, W2[n*2+0], z0);
        z1 = fmaf(hv, W2[n*2+1], z1);
    }
    float m = fmaxf(z0, z1);
    float lse = m + logf(expf(z0-m) + expf(z1-m));
    out[b*2+0] = z0 - lse;
    out[b*2+1] = z1 - lse;
}

extern "C" void kernel_launch(void* const* d_in, const int* in_sizes, int n_in,
                              void* d_out, int out_size, void* d_ws, size_t ws_size,
                              hipStream_t stream){
    const int*   sa  = (const int*)d_in[0];
    const int*   sb  = (const int*)d_in[1];
    const float* emb = (const float*)d_in[2];
    const float* hw1 = (const float*)d_in[3];
    const float* hb1 = (const float*)d_in[4];
    const float* pw1 = (const float*)d_in[5];
    const float* pb1 = (const float*)d_in[6];
    const float* hw2 = (const float*)d_in[7];
    const float* hb2 = (const float*)d_in[8];
    const float* pw2 = (const float*)d_in[9];
    const float* pb2 = (const float*)d_in[10];
    const float* hw3 = (const float*)d_in[11];
    const float* hb3 = (const float*)d_in[12];
    const float* pw3 = (const float*)d_in[13];
    const float* pb3 = (const float*)d_in[14];
    const float* W1  = (const float*)d_in[15];
    const float* b1  = (const float*)d_in[16];
    const float* W2  = (const float*)d_in[17];
    const float* b2  = (const float*)d_in[18];
    float* out = (float*)d_out;

    float* ws    = (float*)d_ws;
    float* S     = ws;                       // 300*16384      = 4,915,200
    float* APOOL = S + 4915200;              // 2*3*3*128*300  =   691,200
    float* AINF  = APOOL + 691200;           // 2*3*128        =       768
    float* PPOOL = AINF + 768;               // 2*3*2*128*6000 = 9,216,000
    float* FEAT  = PPOOL + 9216000;          // 128*44428      = 5,686,784 (padded rows)
    float* HPRE  = FEAT + 5686784;           // 4*128*150      =    76,800
    // time-multiplexed overlays:
    //  - SbfK (10*16448*32 bf16 = 2,631,680 floats) + Wbf overlay PPOOL until hconv9
    //    finishes (k_pdim then overwrites)
    //  - HPART (256*128*160 = 5,242,880 floats) overlays S..AINF (dead by mlp1)
    unsigned short* SBFK = (unsigned short*)PPOOL;
    unsigned short* WBF  = (unsigned short*)(PPOOL + 2631680);
    float* HPART = ws;

    k_embed<<<dim3(64, 5), 256, 0, stream>>>(sa, sb, emb, S);
    k_embedT<<<257, 256, 0, stream>>>(sa, sb, emb, SBFK);
    k_wprep<<<2400, 256, 0, stream>>>(hw1, hw2, hw3, WBF);
    k_hconv9<<<1536, 256, 0, stream>>>(SBFK, WBF, hb1, hb2, hb3, APOOL);
    k_pdim<<<6000, 256, 0, stream>>>(S, pw1,pb1, pw2,pb2, pw3,pb3, PPOOL);
    k_inf<<<256, 256, 0, stream>>>(S, AINF);
    k_pairs<<<dim3(128,3,9), 64, 0, stream>>>(APOOL, FEAT);
    k_infeat<<<1, 384, 0, stream>>>(AINF, FEAT);
    k_pdimfeat<<<dim3(128, 6), 256, 0, stream>>>(PPOOL, FEAT);
    k_mlp1<<<dim3(ZB_), 512, 0, stream>>>(FEAT, W1, HPART);
    k_red<<<dim3(75, 4), 256, 0, stream>>>(HPART, HPRE);
    k_final<<<1, 128, 0, stream>>>(HPRE, b1, W2, b2, out);
}

// Round 8
// 332.374 us; speedup vs baseline: 1.1471x; 1.0547x over previous
//
#include <hip/hip_runtime.h>
#include <math.h>

#define B_    128
#define L_    64
#define C_    300
#define NH_   300
#define K_    20
#define HID_  150
#define N_    (B_*L_)       // 8192
#define N2_   (2*N_)        // 16384
#define NFEAT_ 44427
#define FSTRIDE_ 44428      // padded row stride (16B-aligned rows for float4 loads)
#define ZB_   256           // split-K blocks for mlp1 (1 per CU)
#define KST_  1389          // ceil(NFEAT/32) k-steps
#define KCB_  6             // ceil(KST/ZB) k-steps per block
#define CP_   320           // padded C for bf16 GEMM (mult of 32)
#define NROWS_ 16448        // 257*64: N2_ + pad rows (staging window reads up to +81)
#define PLSZ_ 102400        // weight plane size = 10*CP_*32

typedef __attribute__((ext_vector_type(8))) short bf16x8;
typedef __attribute__((ext_vector_type(4))) float f32x4;

__device__ __forceinline__ float fast_tanh(float x){
    float e = __expf(2.0f*x);
    return 1.0f - 2.0f/(e + 1.0f);
}

__device__ __forceinline__ unsigned short f2bf(float x){
    union { float f; unsigned u; } a; a.f = x;
    unsigned r = a.u + 0x7FFFu + ((a.u >> 16) & 1u);   // RNE
    return (unsigned short)(r >> 16);
}

__device__ __forceinline__ float bf2f(unsigned short h){
    union { unsigned u; float f; } a; a.u = ((unsigned)h) << 16;
    return a.f;
}

// async global->LDS DMA, 16B/lane; lds dest must be wave-uniform base (+lane*16)
__device__ __forceinline__ void gld16(const void* g, void* l){
    __builtin_amdgcn_global_load_lds(
        (__attribute__((address_space(1))) void*)(g),
        (__attribute__((address_space(3))) void*)(l),
        16, 0, 0);
}

// ------------------------------------------------- fused prep: embed | embedT | wprep
// bid [0,320): S[c, s*N+b*64+l] = emb[tok][c]  (64 n-blocks x 5 c-chunks)
// bid [320,577): K-chunk-major bf16 SbfK[kc][n][32]
// bid [577,2977): K-chunk-major bf16 weights WBF[plane][kc][o][32]
// All three are independent; fusing kills 2 launches + their ramp/tail.
__global__ __launch_bounds__(256) void k_prep(const int* __restrict__ sa,
        const int* __restrict__ sb, const float* __restrict__ emb,
        const float* __restrict__ hw1, const float* __restrict__ hw2,
        const float* __restrict__ hw3, float* __restrict__ S,
        unsigned short* __restrict__ sbfK, unsigned short* __restrict__ wbf){
    int bid = blockIdx.x;
    if (bid < 320){
        int n = (bid & 63)*256 + threadIdx.x;      // 0..16383
        int s = n >> 13;
        int nl = n & (N_-1);
        int tok = s ? sb[nl] : sa[nl];
        const float* row = emb + (long)tok * C_;
        int c0 = (bid >> 6) * 60;
        const float4* r4 = (const float4*)(row + c0);
        #pragma unroll
        for (int i = 0; i < 15; ++i){
            float4 f = r4[i];
            long c = c0 + i*4;
            S[c*N2_ + n]     = f.x;
            S[(c+1)*N2_ + n] = f.y;
            S[(c+2)*N2_ + n] = f.z;
            S[(c+3)*N2_ + n] = f.w;
        }
    } else if (bid < 577){
        int bx = bid - 320;
        int w = threadIdx.x >> 6, lane = threadIdx.x & 63;
        for (int i = 0; i < 16; ++i){
            long n = (long)bx*64 + w*16 + i;
            if (n >= NROWS_) return;
            bool pad = (n >= N2_);
            int tok = 0;
            if (!pad) tok = (n >= N_) ? sb[n - N_] : sa[n];
            const float4* er = (const float4*)(emb + (long)tok * C_);
            #pragma unroll
            for (int p = 0; p < 2; ++p){
                int c4 = p*64 + lane;            // float4 index, c = 4*c4
                if (c4 >= CP_/4) continue;
                ushort4 v = {0,0,0,0};
                if (!pad && c4 < 75){
                    float4 f = er[c4];
                    v.x = f2bf(f.x); v.y = f2bf(f.y); v.z = f2bf(f.z); v.w = f2bf(f.w);
                }
                ((ushort4*)(sbfK + (long)(c4 >> 3)*(NROWS_*32) + n*32))[c4 & 7] = v;
            }
        }
    } else {
        int idx = (bid - 577)*256 + threadIdx.x;   // < 614400
        int p = idx / PLSZ_, r = idx % PLSZ_;
        int kc = r / 10240, r2 = r % 10240;
        int o = r2 / 32, ii = r2 % 32;
        int c = kc*32 + ii;
        int WS, j; const float* hw;
        if (p == 0){ WS = 1; j = 0; hw = hw1; }
        else if (p < 3){ WS = 2; j = p - 1; hw = hw2; }
        else { WS = 3; j = p - 3; hw = hw3; }
        float v = (o < NH_ && c < C_) ? hw[((long)o*C_ + c)*WS + j] : 0.0f;
        wbf[idx] = f2bf(v);
    }
}

// ------------------------------------------------- holistic conv via MFMA v10
// = v9 (fused widths, XCD swizzle, tap-major, coalesced K-chunk-major staging,
// pre-swizzled-source octet XOR) + P-buffer aliased into staging buffer 0:
// last chunk's parity is 1 for all WS (NC-1 = 9/19/29), buffer 0 fully drained
// by the final phase's entry barrier -> epilogue may reuse it. LDS 40448->30720B
// -> 5 blocks/CU (was 4): more wave overlap across the per-chunk barrier drain.
__global__ __launch_bounds__(256) void k_hconv9(const unsigned short* __restrict__ sbfK,
        const unsigned short* __restrict__ wbf,
        const float* __restrict__ hb1, const float* __restrict__ hb2,
        const float* __restrict__ hb3, float* __restrict__ apool){
    __shared__ __align__(16) unsigned char LDSU[2][15360];  // per buf: A 5120 | B 10240
    int i0 = blockIdx.x;                       // 0..1535
    int bid = (i0 & 7)*192 + (i0 >> 3);        // XCD-contiguous work id (1536 = 8*192)
    int wsi = bid % 3;  int rr0 = bid / 3;     // WS = wsi+1
    int nhalf = rr0 & 1; int sbx = rr0 >> 1;   // sbx 0..255
    const int WS = wsi + 1;
    const int Lo = 65 - WS;
    const int NC = 10*WS;                      // k-chunks (j-major, kc-minor)
    const int pbase = (WS*(WS-1))/2;           // plane base {0,1,3}
    const float* hb = (WS == 1) ? hb1 : (WS == 2) ? hb2 : hb3;

    int tid = threadIdx.x;
    int w = tid >> 6, lane = tid & 63, col = lane & 15, quad = lane >> 4;
    int s = sbx >> 7, b = sbx & 127;
    long row0 = (long)sbx*64;
    int mt0 = (w>>1)*2;
    int olocb = (w&1)*80 + col;
    int nbase = nhalf*160;
    f32x4 acc[2][5] = {};

    auto stage = [&](int ch, int bi){
        int j = ch/10, kc = ch - 10*j;
        const unsigned short* asrc = sbfK + (long)kc*(NROWS_*32) + (row0 + j)*32;
        const unsigned short* bsrc = wbf + (long)(pbase + j)*PLSZ_
                                         + (long)kc*(CP_*32) + (long)nbase*32;
        unsigned short* AL = (unsigned short*)LDSU[bi];
        unsigned short* BL = (unsigned short*)(LDSU[bi] + 5120);
        #pragma unroll
        for (int q = 0; q < 15; ++q){
            if ((q & 3) != w) continue;        // wave-uniform branch
            int e = q*64 + lane;
            if (q < 5){
                int rr = e >> 2, slot = e & 3;
                int qc = (slot ^ (rr >> 1)) & 3;
                gld16(asrc + rr*32 + qc*8, AL + q*64*8);
            } else {
                int eb = e - 320;              // 0..639
                int o = eb >> 2, slot = eb & 3;
                int qc = (slot ^ (o >> 1)) & 3;
                gld16(bsrc + o*32 + qc*8, BL + (q-5)*64*8);
            }
        }
    };

    stage(0, 0);
    for (int ch = 0; ch < NC; ++ch){
        int cur = ch & 1;
        __syncthreads();                       // drains chunk ch's loads; prior reads done
        if (ch+1 < NC) stage(ch+1, cur^1);
        const unsigned short* AL = (const unsigned short*)LDSU[cur];
        const unsigned short* BL = (const unsigned short*)(LDSU[cur] + 5120);
        int ra0 = mt0*16 + col;
        int ra1 = ra0 + 16;
        bf16x8 a0 = *(const bf16x8*)&AL[(ra0*4 + ((quad ^ (ra0>>1)) & 3))*8];
        bf16x8 a1 = *(const bf16x8*)&AL[(ra1*4 + ((quad ^ (ra1>>1)) & 3))*8];
        #pragma unroll
        for (int ni = 0; ni < 5; ++ni){
            int o = olocb + ni*16;
            bf16x8 bfr = *(const bf16x8*)&BL[(o*4 + ((quad ^ (o>>1)) & 3))*8];
            acc[0][ni] = __builtin_amdgcn_mfma_f32_16x16x32_bf16(a0, bfr, acc[0][ni], 0,0,0);
            acc[1][ni] = __builtin_amdgcn_mfma_f32_16x16x32_bf16(a1, bfr, acc[1][ni], 0,0,0);
        }
    }

    // epilogue reduction; P aliases LDSU[0] (last chunk parity = 1 for all WS)
    float* Pf = (float*)LDSU[0];               // [5][160][3] = 9600 B < 15360
    float rmax[5], rmin[5], rsum[5];
    #pragma unroll
    for (int ni = 0; ni < 5; ++ni){
        int oloc = olocb + ni*16;
        int o = nbase + oloc;
        float bias = (o < NH_) ? hb[o] : 0.0f;
        float vmax = -1e30f, vmin = 1e30f, vsum = 0.0f;
        #pragma unroll
        for (int mi = 0; mi < 2; ++mi){
            int mt = mt0 + mi;
            #pragma unroll
            for (int r = 0; r < 4; ++r){
                int t = mt*16 + quad*4 + r;
                if (t < Lo){
                    float z = acc[mi][ni][r] + bias;
                    vmax = fmaxf(vmax, z); vmin = fminf(vmin, z);
                    vsum += fast_tanh(z);
                }
            }
        }
        for (int m = 16; m < 64; m <<= 1){
            vmax = fmaxf(vmax, __shfl_xor(vmax, m, 64));
            vmin = fminf(vmin, __shfl_xor(vmin, m, 64));
            vsum += __shfl_xor(vsum, m, 64);
        }
        rmax[ni] = vmax; rmin[ni] = vmin; rsum[ni] = vsum;
        if (w < 2 && quad == 0){
            Pf[(ni*160 + oloc)*3 + 0] = vmax;
            Pf[(ni*160 + oloc)*3 + 1] = vmin;
            Pf[(ni*160 + oloc)*3 + 2] = vsum;
        }
    }
    __syncthreads();
    if (w >= 2 && quad == 0){
        #pragma unroll
        for (int ni = 0; ni < 5; ++ni){
            int oloc = olocb + ni*16;
            int o = nbase + oloc;
            if (o < NH_){
                float vmax = fmaxf(rmax[ni], Pf[(ni*160 + oloc)*3 + 0]);
                float vmin = fminf(rmin[ni], Pf[(ni*160 + oloc)*3 + 1]);
                float vsum = rsum[ni] + Pf[(ni*160 + oloc)*3 + 2];
                long base = ((long)((s*3 + (WS-1))*3)) * (long)(B_*NH_) + (long)b*NH_ + o;
                apool[base]                  = fast_tanh(vmax);
                apool[base + (long)(B_*NH_)] = -fast_tanh(vmin);
                apool[base + 2L*(B_*NH_)]    = vsum / (float)Lo;
            }
        }
    }
}

// ------------------------------------------------- fused S-consumers: pdim | inf
// bid [0,6000): per-dim conv + pooling; bid [6000,6256): whole-sentence pools.
__global__ __launch_bounds__(256) void k_sfeat(const float* __restrict__ S,
    const float* __restrict__ pw1, const float* __restrict__ pb1,
    const float* __restrict__ pw2, const float* __restrict__ pb2,
    const float* __restrict__ pw3, const float* __restrict__ pb3,
    float* __restrict__ ppool, float* __restrict__ ainf){
    int bid = blockIdx.x;
    if (bid < 6000){
        long tid = (long)bid*256 + threadIdx.x;   // < 1,536,000
        int k = (int)(tid % 20);
        long r = tid / 20;
        int c = (int)(r % 300); r /= 300;
        int b = (int)(r % 128); int s = (int)(r / 128);
        const float* row = S + (long)c*N2_ + (long)s*N_ + b*64;
        int ck = c*20 + k;
        float w10 = pw1[ck];
        float w20 = pw2[ck*2], w21 = pw2[ck*2+1];
        float w30 = pw3[ck*3], w31 = pw3[ck*3+1], w32 = pw3[ck*3+2];
        float bb1 = pb1[ck], bb2 = pb2[ck], bb3 = pb3[ck];

        float x[64];
        const float4* rp = (const float4*)row;
        #pragma unroll
        for (int i = 0; i < 16; ++i){
            float4 v = rp[i];
            x[i*4+0]=v.x; x[i*4+1]=v.y; x[i*4+2]=v.z; x[i*4+3]=v.w;
        }

        float mx1=-1e30f, mn1=1e30f, mx2=-1e30f, mn2=1e30f, mx3=-1e30f, mn3=1e30f;
        #pragma unroll
        for (int t = 0; t < 64; ++t){
            float z1 = fmaf(w10, x[t], bb1);
            mx1 = fmaxf(mx1, z1); mn1 = fminf(mn1, z1);
        }
        #pragma unroll
        for (int t = 0; t < 63; ++t){
            float z2 = fmaf(w21, x[t+1], fmaf(w20, x[t], bb2));
            mx2 = fmaxf(mx2, z2); mn2 = fminf(mn2, z2);
        }
        #pragma unroll
        for (int t = 0; t < 62; ++t){
            float z3 = fmaf(w32, x[t+2], fmaf(w31, x[t+1], fmaf(w30, x[t], bb3)));
            mx3 = fmaxf(mx3, z3); mn3 = fminf(mn3, z3);
        }

        float outs[6] = { fast_tanh(mx1), -fast_tanh(mn1),
                          fast_tanh(mx2), -fast_tanh(mn2),
                          fast_tanh(mx3), -fast_tanh(mn3) };
        long stride_sw = 128L*6000L;
        long off = (long)b*6000 + (long)c*20 + k;
        #pragma unroll
        for (int wsi = 0; wsi < 3; ++wsi)
            #pragma unroll
            for (int pool = 0; pool < 2; ++pool){
                long slot = (long)((s*3+wsi)*2 + pool);
                ppool[slot*stride_sw + off] = outs[wsi*2+pool];
            }
    } else {
        int sbx = bid - 6000; int s = sbx >> 7, b = sbx & 127;
        int tid = threadIdx.x;
        long base = (long)s*N_ + b*64;
        float vmax = -1e30f, vnmax = -1e30f, vsum = 0.f;
        for (int idx = tid; idx < C_*64; idx += 256){
            int c = idx >> 6, l = idx & 63;
            float v = S[(long)c*N2_ + base + l];
            vmax = fmaxf(vmax, v);
            vnmax = fmaxf(vnmax, -v);
            vsum += v;
        }
        for (int m = 1; m < 64; m <<= 1){
            vmax  = fmaxf(vmax,  __shfl_xor(vmax, m, 64));
            vnmax = fmaxf(vnmax, __shfl_xor(vnmax, m, 64));
            vsum += __shfl_xor(vsum, m, 64);
        }
        __shared__ float red[3][4];
        int w = tid >> 6;
        if ((tid & 63) == 0){ red[0][w]=vmax; red[1][w]=vnmax; red[2][w]=vsum; }
        __syncthreads();
        if (tid == 0){
            float a = fmaxf(fmaxf(red[0][0],red[0][1]),fmaxf(red[0][2],red[0][3]));
            float nn= fmaxf(fmaxf(red[1][0],red[1][1]),fmaxf(red[1][2],red[1][3]));
            float su= red[2][0]+red[2][1]+red[2][2]+red[2][3];
            ainf[(s*3+0)*128 + b] = a;
            ainf[(s*3+1)*128 + b] = nn;
            ainf[(s*3+2)*128 + b] = su / (float)(C_*64);
        }
    }
}

// ------------------------------------------------- fused feature kernel
// bid [0,864): pairs — 4 units/block (wave w owns unit bid*4+w; identical math
//   to the old 64-thread-block version, wave-local shuffles only).
// bid [864,1632): pdimfeat (b = r&127, pw = r>>7).
// bid [1632,1634): infeat (t = (bid-1632)*256 + tid, active t<384).
__global__ __launch_bounds__(256) void k_feat(const float* __restrict__ apool,
        const float* __restrict__ ainf, const float* __restrict__ ppool,
        float* __restrict__ feat){
    __shared__ float X1[20*305];
    __shared__ float X2[20*305];
    int bid = blockIdx.x;
    int tid = threadIdx.x;
    if (bid < 864){
        int w = tid >> 6, lane = tid & 63;
        int u = bid*4 + w;                     // 0..3455
        int b = u / 27, rest = u - 27*b;
        int p = rest / 9, q = rest - 9*p;
        int w1 = q / 3, w2 = q % 3;
        const float* x1 = apool + ((long)((0*3 + w1)*3 + p))*(long)(B_*NH_) + (long)b*NH_;
        const float* x2 = apool + ((long)((1*3 + w2)*3 + p))*(long)(B_*NH_) + (long)b*NH_;
        float dot=0, n1=0, n2=0, d2=0;
        long fb = (long)b*FSTRIDE_;
        long vbase = 24 + (long)p*2721 + (long)q*302;
        for (int i = lane; i < NH_; i += 64){
            float a = x1[i], bb = x2[i];
            dot = fmaf(a, bb, dot); n1 = fmaf(a, a, n1); n2 = fmaf(bb, bb, n2);
            float dd = a - bb + 1e-6f;
            d2 = fmaf(dd, dd, d2);
            feat[fb + vbase + 2 + i] = fabsf(a - bb);
        }
        for (int m = 1; m < 64; m <<= 1){
            dot += __shfl_xor(dot, m, 64);
            n1  += __shfl_xor(n1, m, 64);
            n2  += __shfl_xor(n2, m, 64);
            d2  += __shfl_xor(d2, m, 64);
        }
        if (lane == 0){
            float cosv = dot / fmaxf(sqrtf(n1)*sqrtf(n2), 1e-8f);
            float distv = sqrtf(d2);
            feat[fb + vbase + 0] = cosv;
            feat[fb + vbase + 1] = distv;
            if (w1 == w2){
                feat[fb + p*8 + w1*2 + 0] = cosv;
                feat[fb + p*8 + w1*2 + 1] = distv;
            }
        }
    } else if (bid < 1632){
        int r = bid - 864;
        int b = r & 127, pw = r >> 7;
        int pool = pw / 3, wsi = pw % 3;
        long stride_sw = 128L*6000L;
        const float* x1 = ppool + (long)((0*3+wsi)*2+pool)*stride_sw + (long)b*6000;
        const float* x2 = ppool + (long)((1*3+wsi)*2+pool)*stride_sw + (long)b*6000;
        for (int idx = tid; idx < 6000; idx += 256){
            int c = idx / 20, k = idx - 20*c;
            X1[k*305 + c] = x1[idx];
            X2[k*305 + c] = x2[idx];
        }
        __syncthreads();
        int w = tid >> 6, lane = tid & 63;
        for (int k = w; k < 20; k += 4){
            float dot=0, n1=0, n2=0, d2=0;
            long fb = (long)b*FSTRIDE_ + 8187 + (long)pw*6040 + (long)k*302;
            for (int c = lane; c < C_; c += 64){
                float a = X1[k*305 + c], bb = X2[k*305 + c];
                dot = fmaf(a, bb, dot); n1 = fmaf(a, a, n1); n2 = fmaf(bb, bb, n2);
                float dd = a - bb + 1e-6f;
                d2 = fmaf(dd, dd, d2);
                feat[fb + 2 + c] = fabsf(a - bb);
            }
            for (int m = 1; m < 64; m <<= 1){
                dot += __shfl_xor(dot, m, 64);
                n1  += __shfl_xor(n1, m, 64);
                n2  += __shfl_xor(n2, m, 64);
                d2  += __shfl_xor(d2, m, 64);
            }
            if (lane == 0){
                feat[fb + 0] = dot / fmaxf(sqrtf(n1)*sqrtf(n2), 1e-8f);
                feat[fb + 1] = sqrtf(d2);
            }
        }
    } else {
        int t = (bid - 1632)*256 + tid;
        if (t >= 384) return;
        int b = t & 127, p = t >> 7;
        float x1 = ainf[(0*3+p)*128 + b];
        float x2 = ainf[(1*3+p)*128 + b];
        float cosv = (x1*x2) / fmaxf(fabsf(x1)*fabsf(x2), 1e-8f);
        float distv = fabsf(x1 - x2 + 1e-6f);
        long fb = (long)b*FSTRIDE_;
        feat[fb + p*8 + 6] = cosv;
        feat[fb + p*8 + 7] = distv;
        long vb = 24 + (long)p*2721 + 9L*302;
        feat[fb + vb + 0] = cosv;
        feat[fb + vb + 1] = distv;
        feat[fb + vb + 2] = fabsf(x1 - x2);
    }
}

// ------------------------------------------------- MLP layer 1: MFMA split-K v6
__global__ __launch_bounds__(512) void k_mlp1(const float* __restrict__ feat,
        const float* __restrict__ W1, float* __restrict__ hpart){
    __shared__ __align__(16) unsigned short Bh[2][5120];   // 4 k-octets * 160 n * 8
    __shared__ __align__(16) unsigned short Bl[2][5120];
    int tid = threadIdx.x;
    int w = tid >> 6, lane = tid & 63, col = lane & 15, quad = lane >> 4;
    int z = blockIdx.x;
    int t0 = z * KCB_;
    int ns = KST_ - t0; if (ns > KCB_) ns = KCB_;
    long hbase = (long)z * (128*160);
    int mrow = w*16 + col;                       // wave's m-tile row for A-frag

    if (ns <= 0){
        #pragma unroll
        for (int ni = 0; ni < 10; ++ni)
            #pragma unroll
            for (int r = 0; r < 4; ++r)
                hpart[hbase + (long)(w*16 + quad*4 + r)*160 + ni*16 + col] = 0.0f;
        return;
    }

    // B staging assignment: 2560 (k-pair, n) cells, 5 per thread (constant per step)
    int k2a[5], na[5];
    #pragma unroll
    for (int i = 0; i < 5; ++i){
        int p = i*512 + tid;
        k2a[i] = p / 160; na[i] = p - 160*k2a[i];   // k2 in 0..15 (k = 2*k2), n in 0..159
    }

    const float* arow = feat + (long)mrow * FSTRIDE_;
    float af[8];                 // raw A dwords for current/next step
    float bf0[5], bf1[5];        // raw B pair values
    bf16x8 ah, al;               // current A frags
    f32x4 acc[10] = {};

#define LOADA(STEP) do { \
        int ks_ = t0 + (STEP); \
        int kb_ = ks_*32 + quad*8; \
        if (ks_ < 1388){ \
            float4 f0_ = *(const float4*)(arow + kb_); \
            float4 f1_ = *(const float4*)(arow + kb_ + 4); \
            af[0]=f0_.x; af[1]=f0_.y; af[2]=f0_.z; af[3]=f0_.w; \
            af[4]=f1_.x; af[5]=f1_.y; af[6]=f1_.z; af[7]=f1_.w; \
        } else { \
            _Pragma("unroll") \
            for (int j_ = 0; j_ < 8; ++j_){ \
                int k_ = kb_ + j_; \
                af[j_] = (k_ < NFEAT_) ? arow[k_] : 0.0f; \
            } \
        } } while(0)

#define LOADB(STEP) do { \
        int kb_ = (t0 + (STEP))*32; \
        _Pragma("unroll") \
        for (int i_ = 0; i_ < 5; ++i_){ \
            int k_ = kb_ + 2*k2a[i_]; int n_ = na[i_]; \
            bf0[i_] = (k_   < NFEAT_ && n_ < HID_) ? W1[(long)k_*HID_ + n_]     : 0.0f; \
            bf1[i_] = (k_+1 < NFEAT_ && n_ < HID_) ? W1[(long)(k_+1)*HID_ + n_] : 0.0f; \
        } } while(0)

#define CVTA() do { \
        _Pragma("unroll") \
        for (int j_ = 0; j_ < 8; ++j_){ \
            unsigned short h_ = f2bf(af[j_]); \
            unsigned short l_ = f2bf(af[j_] - bf2f(h_)); \
            ah[j_] = (short)h_; al[j_] = (short)l_; \
        } } while(0)

#define WRITEB(BUF) do { \
        _Pragma("unroll") \
        for (int i_ = 0; i_ < 5; ++i_){ \
            int k2_ = k2a[i_]; int n_ = na[i_]; \
            int q_ = k2_ >> 2, off_ = k2_ & 3; \
            unsigned short h0_ = f2bf(bf0[i_]); \
            unsigned short l0_ = f2bf(bf0[i_] - bf2f(h0_)); \
            unsigned short h1_ = f2bf(bf1[i_]); \
            unsigned short l1_ = f2bf(bf1[i_] - bf2f(h1_)); \
            int ui_ = (q_*160 + n_)*4 + off_; \
            ((unsigned*)Bh[BUF])[ui_] = (unsigned)h0_ | ((unsigned)h1_ << 16); \
            ((unsigned*)Bl[BUF])[ui_] = (unsigned)l0_ | ((unsigned)l1_ << 16); \
        } } while(0)

    // prologue: fetch step 0, stage B(0) into buf 0
    LOADB(0);
    LOADA(0);
    WRITEB(0);

    for (int t = 0; t < ns; ++t){
        __syncthreads();                       // B(t) LDS writes visible to all waves
        CVTA();                                // A(t) raw -> frags (waits its vmcnt)
        bool more = (t+1 < ns);
        if (more){ LOADA(t+1); LOADB(t+1); }   // issue next-step global loads early
        int bi = t & 1;
        #pragma unroll
        for (int ni = 0; ni < 10; ++ni){
            bf16x8 bh = *(const bf16x8*)&Bh[bi][(quad*160 + ni*16 + col)*8];
            bf16x8 bl = *(const bf16x8*)&Bl[bi][(quad*160 + ni*16 + col)*8];
            acc[ni] = __builtin_amdgcn_mfma_f32_16x16x32_bf16(ah, bh, acc[ni], 0,0,0);
            acc[ni] = __builtin_amdgcn_mfma_f32_16x16x32_bf16(al, bh, acc[ni], 0,0,0);
            acc[ni] = __builtin_amdgcn_mfma_f32_16x16x32_bf16(ah, bl, acc[ni], 0,0,0);
        }
        if (more) WRITEB((t+1)&1);             // waits B(t+1) vmcnt; other buffer
    }

#undef LOADA
#undef LOADB
#undef CVTA
#undef WRITEB

    #pragma unroll
    for (int ni = 0; ni < 10; ++ni)
        #pragma unroll
        for (int r = 0; r < 4; ++r)
            hpart[hbase + (long)(w*16 + quad*4 + r)*160 + ni*16 + col] = acc[ni][r];
}

// ------------------------------------------------- reduce split-K partials v2
// grid (75, 4): y-chunk sums 64 z's -> 300 blocks. k_final sums the 4 slices.
__global__ void k_red(const float* __restrict__ hpart, float* __restrict__ hpre4){
    int t = blockIdx.x*256 + threadIdx.x;
    if (t >= 128*HID_) return;
    int y = blockIdx.y;
    int b = t / HID_, n = t % HID_;
    float s = 0.0f;
    int z0 = y*64;
    for (int z = z0; z < z0+64; ++z)
        s += hpart[(long)z*(128*160) + (long)b*160 + n];
    hpre4[(long)y*(128*HID_) + t] = s;
}

// ------------------------------------------------- tanh + layer2 + log_softmax
__global__ void k_final(const float* __restrict__ hpre4, const float* __restrict__ b1,
        const float* __restrict__ W2, const float* __restrict__ b2,
        float* __restrict__ out){
    int b = threadIdx.x;
    if (b >= 128) return;
    float z0 = b2[0], z1 = b2[1];
    for (int n = 0; n < HID_; ++n){
        int idx = b*HID_ + n;
        float hp = hpre4[idx] + hpre4[19200 + idx] + hpre4[38400 + idx] + hpre4[57600 + idx];
        float hv = fast_tanh(hp + b1[n]);
        z0 = fmaf(hv, W2[n*2+0], z0);
        z1 = fmaf(hv, W2[n*2+1], z1);
    }
    float m = fmaxf(z0, z1);
    float lse = m + logf(expf(z0-m) + expf(z1-m));
    out[b*2+0] = z0 - lse;
    out[b*2+1] = z1 - lse;
}

extern "C" void kernel_launch(void* const* d_in, const int* in_sizes, int n_in,
                              void* d_out, int out_size, void* d_ws, size_t ws_size,
                              hipStream_t stream){
    const int*   sa  = (const int*)d_in[0];
    const int*   sb  = (const int*)d_in[1];
    const float* emb = (const float*)d_in[2];
    const float* hw1 = (const float*)d_in[3];
    const float* hb1 = (const float*)d_in[4];
    const float* pw1 = (const float*)d_in[5];
    const float* pb1 = (const float*)d_in[6];
    const float* hw2 = (const float*)d_in[7];
    const float* hb2 = (const float*)d_in[8];
    const float* pw2 = (const float*)d_in[9];
    const float* pb2 = (const float*)d_in[10];
    const float* hw3 = (const float*)d_in[11];
    const float* hb3 = (const float*)d_in[12];
    const float* pw3 = (const float*)d_in[13];
    const float* pb3 = (const float*)d_in[14];
    const float* W1  = (const float*)d_in[15];
    const float* b1  = (const float*)d_in[16];
    const float* W2  = (const float*)d_in[17];
    const float* b2  = (const float*)d_in[18];
    float* out = (float*)d_out;

    float* ws    = (float*)d_ws;
    float* S     = ws;                       // 300*16384      = 4,915,200
    float* APOOL = S + 4915200;              // 2*3*3*128*300  =   691,200
    float* AINF  = APOOL + 691200;           // 2*3*128        =       768
    float* PPOOL = AINF + 768;               // 2*3*2*128*6000 = 9,216,000
    float* FEAT  = PPOOL + 9216000;          // 128*44428      = 5,686,784 (padded rows)
    float* HPRE  = FEAT + 5686784;           // 4*128*150      =    76,800
    // time-multiplexed overlays:
    //  - SbfK (10*16448*32 bf16 = 2,631,680 floats) + Wbf overlay PPOOL until hconv9
    //    finishes (k_sfeat/pdim then overwrites)
    //  - HPART (256*128*160 = 5,242,880 floats) overlays S..AINF (dead by mlp1)
    unsigned short* SBFK = (unsigned short*)PPOOL;
    unsigned short* WBF  = (unsigned short*)(PPOOL + 2631680);
    float* HPART = ws;

    k_prep<<<2977, 256, 0, stream>>>(sa, sb, emb, hw1, hw2, hw3, S, SBFK, WBF);
    k_hconv9<<<1536, 256, 0, stream>>>(SBFK, WBF, hb1, hb2, hb3, APOOL);
    k_sfeat<<<6256, 256, 0, stream>>>(S, pw1,pb1, pw2,pb2, pw3,pb3, PPOOL, AINF);
    k_feat<<<1634, 256, 0, stream>>>(APOOL, AINF, PPOOL, FEAT);
    k_mlp1<<<dim3(ZB_), 512, 0, stream>>>(FEAT, W1, HPART);
    k_red<<<dim3(75, 4), 256, 0, stream>>>(HPART, HPRE);
    k_final<<<1, 128, 0, stream>>>(HPRE, b1, W2, b2, out);
}

// Round 9
// 317.761 us; speedup vs baseline: 1.1998x; 1.0460x over previous
//
#include <hip/hip_runtime.h>
#include <math.h>

#define B_    128
#define L_    64
#define C_    300
#define NH_   300
#define K_    20
#define HID_  150
#define N_    (B_*L_)       // 8192
#define N2_   (2*N_)        // 16384
#define NFEAT_ 44427
#define FSTRIDE_ 44428      // padded row stride (16B-aligned rows for float4 loads)
#define ZB_   256           // split-K blocks for mlp1 (1 per CU)
#define KST_  1389          // ceil(NFEAT/32) k-steps
#define KCB_  6             // ceil(KST/ZB) k-steps per block
#define CP_   320           // padded C for bf16 GEMM (mult of 32)
#define NROWS_ 16448        // 257*64: N2_ + pad rows (staging window reads up to +81)
#define PLSZ_ 102400        // weight plane size = 10*CP_*32

typedef __attribute__((ext_vector_type(8))) short bf16x8;
typedef __attribute__((ext_vector_type(4))) float f32x4;

__device__ __forceinline__ float fast_tanh(float x){
    float e = __expf(2.0f*x);
    return 1.0f - 2.0f/(e + 1.0f);
}

__device__ __forceinline__ unsigned short f2bf(float x){
    union { float f; unsigned u; } a; a.f = x;
    unsigned r = a.u + 0x7FFFu + ((a.u >> 16) & 1u);   // RNE
    return (unsigned short)(r >> 16);
}

__device__ __forceinline__ float bf2f(unsigned short h){
    union { unsigned u; float f; } a; a.u = ((unsigned)h) << 16;
    return a.f;
}

// async global->LDS DMA, 16B/lane; lds dest must be wave-uniform base (+lane*16)
__device__ __forceinline__ void gld16(const void* g, void* l){
    __builtin_amdgcn_global_load_lds(
        (__attribute__((address_space(1))) void*)(g),
        (__attribute__((address_space(3))) void*)(l),
        16, 0, 0);
}

// ------------------------------------------------- fused prep: embed | embedT | wprep
// bid [0,320): S[c, s*N+b*64+l] = emb[tok][c]  (64 n-blocks x 5 c-chunks)
// bid [320,577): K-chunk-major bf16 SbfK[kc][n][32]
// bid [577,2977): K-chunk-major bf16 weights WBF[plane][kc][o][32]
__global__ __launch_bounds__(256) void k_prep(const int* __restrict__ sa,
        const int* __restrict__ sb, const float* __restrict__ emb,
        const float* __restrict__ hw1, const float* __restrict__ hw2,
        const float* __restrict__ hw3, float* __restrict__ S,
        unsigned short* __restrict__ sbfK, unsigned short* __restrict__ wbf){
    int bid = blockIdx.x;
    if (bid < 320){
        int n = (bid & 63)*256 + threadIdx.x;      // 0..16383
        int s = n >> 13;
        int nl = n & (N_-1);
        int tok = s ? sb[nl] : sa[nl];
        const float* row = emb + (long)tok * C_;
        int c0 = (bid >> 6) * 60;
        const float4* r4 = (const float4*)(row + c0);
        #pragma unroll
        for (int i = 0; i < 15; ++i){
            float4 f = r4[i];
            long c = c0 + i*4;
            S[c*N2_ + n]     = f.x;
            S[(c+1)*N2_ + n] = f.y;
            S[(c+2)*N2_ + n] = f.z;
            S[(c+3)*N2_ + n] = f.w;
        }
    } else if (bid < 577){
        int bx = bid - 320;
        int w = threadIdx.x >> 6, lane = threadIdx.x & 63;
        for (int i = 0; i < 16; ++i){
            long n = (long)bx*64 + w*16 + i;
            if (n >= NROWS_) return;
            bool pad = (n >= N2_);
            int tok = 0;
            if (!pad) tok = (n >= N_) ? sb[n - N_] : sa[n];
            const float4* er = (const float4*)(emb + (long)tok * C_);
            #pragma unroll
            for (int p = 0; p < 2; ++p){
                int c4 = p*64 + lane;            // float4 index, c = 4*c4
                if (c4 >= CP_/4) continue;
                ushort4 v = {0,0,0,0};
                if (!pad && c4 < 75){
                    float4 f = er[c4];
                    v.x = f2bf(f.x); v.y = f2bf(f.y); v.z = f2bf(f.z); v.w = f2bf(f.w);
                }
                ((ushort4*)(sbfK + (long)(c4 >> 3)*(NROWS_*32) + n*32))[c4 & 7] = v;
            }
        }
    } else {
        int idx = (bid - 577)*256 + threadIdx.x;   // < 614400
        int p = idx / PLSZ_, r = idx % PLSZ_;
        int kc = r / 10240, r2 = r % 10240;
        int o = r2 / 32, ii = r2 % 32;
        int c = kc*32 + ii;
        int WS, j; const float* hw;
        if (p == 0){ WS = 1; j = 0; hw = hw1; }
        else if (p < 3){ WS = 2; j = p - 1; hw = hw2; }
        else { WS = 3; j = p - 3; hw = hw3; }
        float v = (o < NH_ && c < C_) ? hw[((long)o*C_ + c)*WS + j] : 0.0f;
        wbf[idx] = f2bf(v);
    }
}

// ------------------------------------------------- holistic conv via MFMA v10
// v9 (fused widths, XCD swizzle, tap-major, coalesced K-chunk-major staging,
// pre-swizzled-source octet XOR) + P-buffer aliased into staging buffer 0.
__global__ __launch_bounds__(256) void k_hconv9(const unsigned short* __restrict__ sbfK,
        const unsigned short* __restrict__ wbf,
        const float* __restrict__ hb1, const float* __restrict__ hb2,
        const float* __restrict__ hb3, float* __restrict__ apool){
    __shared__ __align__(16) unsigned char LDSU[2][15360];  // per buf: A 5120 | B 10240
    int i0 = blockIdx.x;                       // 0..1535
    int bid = (i0 & 7)*192 + (i0 >> 3);        // XCD-contiguous work id (1536 = 8*192)
    int wsi = bid % 3;  int rr0 = bid / 3;     // WS = wsi+1
    int nhalf = rr0 & 1; int sbx = rr0 >> 1;   // sbx 0..255
    const int WS = wsi + 1;
    const int Lo = 65 - WS;
    const int NC = 10*WS;                      // k-chunks (j-major, kc-minor)
    const int pbase = (WS*(WS-1))/2;           // plane base {0,1,3}
    const float* hb = (WS == 1) ? hb1 : (WS == 2) ? hb2 : hb3;

    int tid = threadIdx.x;
    int w = tid >> 6, lane = tid & 63, col = lane & 15, quad = lane >> 4;
    int s = sbx >> 7, b = sbx & 127;
    long row0 = (long)sbx*64;
    int mt0 = (w>>1)*2;
    int olocb = (w&1)*80 + col;
    int nbase = nhalf*160;
    f32x4 acc[2][5] = {};

    auto stage = [&](int ch, int bi){
        int j = ch/10, kc = ch - 10*j;
        const unsigned short* asrc = sbfK + (long)kc*(NROWS_*32) + (row0 + j)*32;
        const unsigned short* bsrc = wbf + (long)(pbase + j)*PLSZ_
                                         + (long)kc*(CP_*32) + (long)nbase*32;
        unsigned short* AL = (unsigned short*)LDSU[bi];
        unsigned short* BL = (unsigned short*)(LDSU[bi] + 5120);
        #pragma unroll
        for (int q = 0; q < 15; ++q){
            if ((q & 3) != w) continue;        // wave-uniform branch
            int e = q*64 + lane;
            if (q < 5){
                int rr = e >> 2, slot = e & 3;
                int qc = (slot ^ (rr >> 1)) & 3;
                gld16(asrc + rr*32 + qc*8, AL + q*64*8);
            } else {
                int eb = e - 320;              // 0..639
                int o = eb >> 2, slot = eb & 3;
                int qc = (slot ^ (o >> 1)) & 3;
                gld16(bsrc + o*32 + qc*8, BL + (q-5)*64*8);
            }
        }
    };

    stage(0, 0);
    for (int ch = 0; ch < NC; ++ch){
        int cur = ch & 1;
        __syncthreads();                       // drains chunk ch's loads; prior reads done
        if (ch+1 < NC) stage(ch+1, cur^1);
        const unsigned short* AL = (const unsigned short*)LDSU[cur];
        const unsigned short* BL = (const unsigned short*)(LDSU[cur] + 5120);
        int ra0 = mt0*16 + col;
        int ra1 = ra0 + 16;
        bf16x8 a0 = *(const bf16x8*)&AL[(ra0*4 + ((quad ^ (ra0>>1)) & 3))*8];
        bf16x8 a1 = *(const bf16x8*)&AL[(ra1*4 + ((quad ^ (ra1>>1)) & 3))*8];
        #pragma unroll
        for (int ni = 0; ni < 5; ++ni){
            int o = olocb + ni*16;
            bf16x8 bfr = *(const bf16x8*)&BL[(o*4 + ((quad ^ (o>>1)) & 3))*8];
            acc[0][ni] = __builtin_amdgcn_mfma_f32_16x16x32_bf16(a0, bfr, acc[0][ni], 0,0,0);
            acc[1][ni] = __builtin_amdgcn_mfma_f32_16x16x32_bf16(a1, bfr, acc[1][ni], 0,0,0);
        }
    }

    // epilogue reduction; P aliases LDSU[0] (last chunk parity = 1 for all WS)
    float* Pf = (float*)LDSU[0];               // [5][160][3] = 9600 B < 15360
    float rmax[5], rmin[5], rsum[5];
    #pragma unroll
    for (int ni = 0; ni < 5; ++ni){
        int oloc = olocb + ni*16;
        int o = nbase + oloc;
        float bias = (o < NH_) ? hb[o] : 0.0f;
        float vmax = -1e30f, vmin = 1e30f, vsum = 0.0f;
        #pragma unroll
        for (int mi = 0; mi < 2; ++mi){
            int mt = mt0 + mi;
            #pragma unroll
            for (int r = 0; r < 4; ++r){
                int t = mt*16 + quad*4 + r;
                if (t < Lo){
                    float z = acc[mi][ni][r] + bias;
                    vmax = fmaxf(vmax, z); vmin = fminf(vmin, z);
                    vsum += fast_tanh(z);
                }
            }
        }
        for (int m = 16; m < 64; m <<= 1){
            vmax = fmaxf(vmax, __shfl_xor(vmax, m, 64));
            vmin = fminf(vmin, __shfl_xor(vmin, m, 64));
            vsum += __shfl_xor(vsum, m, 64);
        }
        rmax[ni] = vmax; rmin[ni] = vmin; rsum[ni] = vsum;
        if (w < 2 && quad == 0){
            Pf[(ni*160 + oloc)*3 + 0] = vmax;
            Pf[(ni*160 + oloc)*3 + 1] = vmin;
            Pf[(ni*160 + oloc)*3 + 2] = vsum;
        }
    }
    __syncthreads();
    if (w >= 2 && quad == 0){
        #pragma unroll
        for (int ni = 0; ni < 5; ++ni){
            int oloc = olocb + ni*16;
            int o = nbase + oloc;
            if (o < NH_){
                float vmax = fmaxf(rmax[ni], Pf[(ni*160 + oloc)*3 + 0]);
                float vmin = fminf(rmin[ni], Pf[(ni*160 + oloc)*3 + 1]);
                float vsum = rsum[ni] + Pf[(ni*160 + oloc)*3 + 2];
                long base = ((long)((s*3 + (WS-1))*3)) * (long)(B_*NH_) + (long)b*NH_ + o;
                apool[base]                  = fast_tanh(vmax);
                apool[base + (long)(B_*NH_)] = -fast_tanh(vmin);
                apool[base + 2L*(B_*NH_)]    = vsum / (float)Lo;
            }
        }
    }
}

// ------------------------------------------------- fused S-consumers: pdim | inf
// bid [0,6000): per-dim conv + pooling v3 — chunked row (2x16 double-buffer,
//   max 32 row-regs live vs v2's 64 -> VGPR ~100->~70, occupancy up) + ws=1
//   monotonicity shortcut: max_t fmaf(w,x[t],b) = fmaf(w, w>=0?xmax:xmin, b)
//   (fma monotone in x for fixed-sign w -> bit-identical; saves ~190 ops).
// bid [6000,6256): whole-sentence pools.
__global__ __launch_bounds__(256) void k_sfeat(const float* __restrict__ S,
    const float* __restrict__ pw1, const float* __restrict__ pb1,
    const float* __restrict__ pw2, const float* __restrict__ pb2,
    const float* __restrict__ pw3, const float* __restrict__ pb3,
    float* __restrict__ ppool, float* __restrict__ ainf){
    int bid = blockIdx.x;
    if (bid < 6000){
        long tid = (long)bid*256 + threadIdx.x;   // < 1,536,000
        int k = (int)(tid % 20);
        long r = tid / 20;
        int c = (int)(r % 300); r /= 300;
        int b = (int)(r % 128); int s = (int)(r / 128);
        const float4* rp = (const float4*)(S + (long)c*N2_ + (long)s*N_ + b*64);
        int ck = c*20 + k;
        float w10 = pw1[ck];
        float w20 = pw2[ck*2], w21 = pw2[ck*2+1];
        float w30 = pw3[ck*3], w31 = pw3[ck*3+1], w32 = pw3[ck*3+2];
        float bb1 = pb1[ck], bb2 = pb2[ck], bb3 = pb3[ck];

        float xmax=-1e30f, xmin=1e30f, mx2=-1e30f, mn2=1e30f, mx3=-1e30f, mn3=1e30f;
        float p1 = 0.0f, p2 = 0.0f;            // carries: x[base-1], x[base-2]
        float ea[16], eb[16];

#define LOADC(E, CH) do { \
        _Pragma("unroll") \
        for (int i_ = 0; i_ < 4; ++i_){ \
            float4 v_ = rp[(CH)*4 + i_]; \
            E[i_*4+0]=v_.x; E[i_*4+1]=v_.y; E[i_*4+2]=v_.z; E[i_*4+3]=v_.w; \
        } } while(0)

        // window coverage: conv2 pairs = 15x4 in-chunk + 3 cross = 63;
        // conv3 triples = 14x4 in-chunk + 2x3 cross = 62. t ascends; max exact.
#define PROCC(E, FIRST) do { \
        if (!(FIRST)){ \
            float z2c_ = fmaf(w21, E[0], fmaf(w20, p1, bb2)); \
            mx2 = fmaxf(mx2, z2c_); mn2 = fminf(mn2, z2c_); \
            float z3a_ = fmaf(w32, E[0], fmaf(w31, p1, fmaf(w30, p2, bb3))); \
            mx3 = fmaxf(mx3, z3a_); mn3 = fminf(mn3, z3a_); \
            float z3b_ = fmaf(w32, E[1], fmaf(w31, E[0], fmaf(w30, p1, bb3))); \
            mx3 = fmaxf(mx3, z3b_); mn3 = fminf(mn3, z3b_); \
        } \
        _Pragma("unroll") \
        for (int i_ = 0; i_ < 16; ++i_){ \
            xmax = fmaxf(xmax, E[i_]); xmin = fminf(xmin, E[i_]); \
        } \
        _Pragma("unroll") \
        for (int i_ = 0; i_ < 15; ++i_){ \
            float z2_ = fmaf(w21, E[i_+1], fmaf(w20, E[i_], bb2)); \
            mx2 = fmaxf(mx2, z2_); mn2 = fminf(mn2, z2_); \
        } \
        _Pragma("unroll") \
        for (int i_ = 0; i_ < 14; ++i_){ \
            float z3_ = fmaf(w32, E[i_+2], fmaf(w31, E[i_+1], fmaf(w30, E[i_], bb3))); \
            mx3 = fmaxf(mx3, z3_); mn3 = fminf(mn3, z3_); \
        } \
        p2 = E[14]; p1 = E[15]; } while(0)

        LOADC(ea, 0);
        LOADC(eb, 1);
        PROCC(ea, true);
        LOADC(ea, 2);                           // reuse ea regs for chunk 2
        PROCC(eb, false);
        LOADC(eb, 3);
        PROCC(ea, false);
        PROCC(eb, false);
#undef LOADC
#undef PROCC

        float hi = (w10 >= 0.0f) ? xmax : xmin;
        float lo = (w10 >= 0.0f) ? xmin : xmax;
        float outs[6] = { fast_tanh(fmaf(w10, hi, bb1)), -fast_tanh(fmaf(w10, lo, bb1)),
                          fast_tanh(mx2), -fast_tanh(mn2),
                          fast_tanh(mx3), -fast_tanh(mn3) };
        long stride_sw = 128L*6000L;
        long off = (long)b*6000 + (long)c*20 + k;
        #pragma unroll
        for (int wsi = 0; wsi < 3; ++wsi)
            #pragma unroll
            for (int pool = 0; pool < 2; ++pool){
                long slot = (long)((s*3+wsi)*2 + pool);
                ppool[slot*stride_sw + off] = outs[wsi*2+pool];
            }
    } else {
        int sbx = bid - 6000; int s = sbx >> 7, b = sbx & 127;
        int tid = threadIdx.x;
        long base = (long)s*N_ + b*64;
        float vmax = -1e30f, vnmax = -1e30f, vsum = 0.f;
        for (int idx = tid; idx < C_*64; idx += 256){
            int c = idx >> 6, l = idx & 63;
            float v = S[(long)c*N2_ + base + l];
            vmax = fmaxf(vmax, v);
            vnmax = fmaxf(vnmax, -v);
            vsum += v;
        }
        for (int m = 1; m < 64; m <<= 1){
            vmax  = fmaxf(vmax,  __shfl_xor(vmax, m, 64));
            vnmax = fmaxf(vnmax, __shfl_xor(vnmax, m, 64));
            vsum += __shfl_xor(vsum, m, 64);
        }
        __shared__ float red[3][4];
        int w = tid >> 6;
        if ((tid & 63) == 0){ red[0][w]=vmax; red[1][w]=vnmax; red[2][w]=vsum; }
        __syncthreads();
        if (tid == 0){
            float a = fmaxf(fmaxf(red[0][0],red[0][1]),fmaxf(red[0][2],red[0][3]));
            float nn= fmaxf(fmaxf(red[1][0],red[1][1]),fmaxf(red[1][2],red[1][3]));
            float su= red[2][0]+red[2][1]+red[2][2]+red[2][3];
            ainf[(s*3+0)*128 + b] = a;
            ainf[(s*3+1)*128 + b] = nn;
            ainf[(s*3+2)*128 + b] = su / (float)(C_*64);
        }
    }
}

// ------------------------------------------------- fused feature kernel
// bid [0,864): pairs — 4 units/block. bid [864,1632): pdimfeat.
// bid [1632,1634): infeat.
__global__ __launch_bounds__(256) void k_feat(const float* __restrict__ apool,
        const float* __restrict__ ainf, const float* __restrict__ ppool,
        float* __restrict__ feat){
    __shared__ float X1[20*305];
    __shared__ float X2[20*305];
    int bid = blockIdx.x;
    int tid = threadIdx.x;
    if (bid < 864){
        int w = tid >> 6, lane = tid & 63;
        int u = bid*4 + w;                     // 0..3455
        int b = u / 27, rest = u - 27*b;
        int p = rest / 9, q = rest - 9*p;
        int w1 = q / 3, w2 = q % 3;
        const float* x1 = apool + ((long)((0*3 + w1)*3 + p))*(long)(B_*NH_) + (long)b*NH_;
        const float* x2 = apool + ((long)((1*3 + w2)*3 + p))*(long)(B_*NH_) + (long)b*NH_;
        float dot=0, n1=0, n2=0, d2=0;
        long fb = (long)b*FSTRIDE_;
        long vbase = 24 + (long)p*2721 + (long)q*302;
        for (int i = lane; i < NH_; i += 64){
            float a = x1[i], bb = x2[i];
            dot = fmaf(a, bb, dot); n1 = fmaf(a, a, n1); n2 = fmaf(bb, bb, n2);
            float dd = a - bb + 1e-6f;
            d2 = fmaf(dd, dd, d2);
            feat[fb + vbase + 2 + i] = fabsf(a - bb);
        }
        for (int m = 1; m < 64; m <<= 1){
            dot += __shfl_xor(dot, m, 64);
            n1  += __shfl_xor(n1, m, 64);
            n2  += __shfl_xor(n2, m, 64);
            d2  += __shfl_xor(d2, m, 64);
        }
        if (lane == 0){
            float cosv = dot / fmaxf(sqrtf(n1)*sqrtf(n2), 1e-8f);
            float distv = sqrtf(d2);
            feat[fb + vbase + 0] = cosv;
            feat[fb + vbase + 1] = distv;
            if (w1 == w2){
                feat[fb + p*8 + w1*2 + 0] = cosv;
                feat[fb + p*8 + w1*2 + 1] = distv;
            }
        }
    } else if (bid < 1632){
        int r = bid - 864;
        int b = r & 127, pw = r >> 7;
        int pool = pw / 3, wsi = pw % 3;
        long stride_sw = 128L*6000L;
        const float* x1 = ppool + (long)((0*3+wsi)*2+pool)*stride_sw + (long)b*6000;
        const float* x2 = ppool + (long)((1*3+wsi)*2+pool)*stride_sw + (long)b*6000;
        for (int idx = tid; idx < 6000; idx += 256){
            int c = idx / 20, k = idx - 20*c;
            X1[k*305 + c] = x1[idx];
            X2[k*305 + c] = x2[idx];
        }
        __syncthreads();
        int w = tid >> 6, lane = tid & 63;
        for (int k = w; k < 20; k += 4){
            float dot=0, n1=0, n2=0, d2=0;
            long fb = (long)b*FSTRIDE_ + 8187 + (long)pw*6040 + (long)k*302;
            for (int c = lane; c < C_; c += 64){
                float a = X1[k*305 + c], bb = X2[k*305 + c];
                dot = fmaf(a, bb, dot); n1 = fmaf(a, a, n1); n2 = fmaf(bb, bb, n2);
                float dd = a - bb + 1e-6f;
                d2 = fmaf(dd, dd, d2);
                feat[fb + 2 + c] = fabsf(a - bb);
            }
            for (int m = 1; m < 64; m <<= 1){
                dot += __shfl_xor(dot, m, 64);
                n1  += __shfl_xor(n1, m, 64);
                n2  += __shfl_xor(n2, m, 64);
                d2  += __shfl_xor(d2, m, 64);
            }
            if (lane == 0){
                feat[fb + 0] = dot / fmaxf(sqrtf(n1)*sqrtf(n2), 1e-8f);
                feat[fb + 1] = sqrtf(d2);
            }
        }
    } else {
        int t = (bid - 1632)*256 + tid;
        if (t >= 384) return;
        int b = t & 127, p = t >> 7;
        float x1 = ainf[(0*3+p)*128 + b];
        float x2 = ainf[(1*3+p)*128 + b];
        float cosv = (x1*x2) / fmaxf(fabsf(x1)*fabsf(x2), 1e-8f);
        float distv = fabsf(x1 - x2 + 1e-6f);
        long fb = (long)b*FSTRIDE_;
        feat[fb + p*8 + 6] = cosv;
        feat[fb + p*8 + 7] = distv;
        long vb = 24 + (long)p*2721 + 9L*302;
        feat[fb + vb + 0] = cosv;
        feat[fb + vb + 1] = distv;
        feat[fb + vb + 2] = fabsf(x1 - x2);
    }
}

// ------------------------------------------------- MLP layer 1: MFMA split-K v6
__global__ __launch_bounds__(512) void k_mlp1(const float* __restrict__ feat,
        const float* __restrict__ W1, float* __restrict__ hpart){
    __shared__ __align__(16) unsigned short Bh[2][5120];   // 4 k-octets * 160 n * 8
    __shared__ __align__(16) unsigned short Bl[2][5120];
    int tid = threadIdx.x;
    int w = tid >> 6, lane = tid & 63, col = lane & 15, quad = lane >> 4;
    int z = blockIdx.x;
    int t0 = z * KCB_;
    int ns = KST_ - t0; if (ns > KCB_) ns = KCB_;
    long hbase = (long)z * (128*160);
    int mrow = w*16 + col;                       // wave's m-tile row for A-frag

    if (ns <= 0){
        #pragma unroll
        for (int ni = 0; ni < 10; ++ni)
            #pragma unroll
            for (int r = 0; r < 4; ++r)
                hpart[hbase + (long)(w*16 + quad*4 + r)*160 + ni*16 + col] = 0.0f;
        return;
    }

    // B staging assignment: 2560 (k-pair, n) cells, 5 per thread (constant per step)
    int k2a[5], na[5];
    #pragma unroll
    for (int i = 0; i < 5; ++i){
        int p = i*512 + tid;
        k2a[i] = p / 160; na[i] = p - 160*k2a[i];   // k2 in 0..15 (k = 2*k2), n in 0..159
    }

    const float* arow = feat + (long)mrow * FSTRIDE_;
    float af[8];                 // raw A dwords for current/next step
    float bf0[5], bf1[5];        // raw B pair values
    bf16x8 ah, al;               // current A frags
    f32x4 acc[10] = {};

#define LOADA(STEP) do { \
        int ks_ = t0 + (STEP); \
        int kb_ = ks_*32 + quad*8; \
        if (ks_ < 1388){ \
            float4 f0_ = *(const float4*)(arow + kb_); \
            float4 f1_ = *(const float4*)(arow + kb_ + 4); \
            af[0]=f0_.x; af[1]=f0_.y; af[2]=f0_.z; af[3]=f0_.w; \
            af[4]=f1_.x; af[5]=f1_.y; af[6]=f1_.z; af[7]=f1_.w; \
        } else { \
            _Pragma("unroll") \
            for (int j_ = 0; j_ < 8; ++j_){ \
                int k_ = kb_ + j_; \
                af[j_] = (k_ < NFEAT_) ? arow[k_] : 0.0f; \
            } \
        } } while(0)

#define LOADB(STEP) do { \
        int kb_ = (t0 + (STEP))*32; \
        _Pragma("unroll") \
        for (int i_ = 0; i_ < 5; ++i_){ \
            int k_ = kb_ + 2*k2a[i_]; int n_ = na[i_]; \
            bf0[i_] = (k_   < NFEAT_ && n_ < HID_) ? W1[(long)k_*HID_ + n_]     : 0.0f; \
            bf1[i_] = (k_+1 < NFEAT_ && n_ < HID_) ? W1[(long)(k_+1)*HID_ + n_] : 0.0f; \
        } } while(0)

#define CVTA() do { \
        _Pragma("unroll") \
        for (int j_ = 0; j_ < 8; ++j_){ \
            unsigned short h_ = f2bf(af[j_]); \
            unsigned short l_ = f2bf(af[j_] - bf2f(h_)); \
            ah[j_] = (short)h_; al[j_] = (short)l_; \
        } } while(0)

#define WRITEB(BUF) do { \
        _Pragma("unroll") \
        for (int i_ = 0; i_ < 5; ++i_){ \
            int k2_ = k2a[i_]; int n_ = na[i_]; \
            int q_ = k2_ >> 2, off_ = k2_ & 3; \
            unsigned short h0_ = f2bf(bf0[i_]); \
            unsigned short l0_ = f2bf(bf0[i_] - bf2f(h0_)); \
            unsigned short h1_ = f2bf(bf1[i_]); \
            unsigned short l1_ = f2bf(bf1[i_] - bf2f(h1_)); \
            int ui_ = (q_*160 + n_)*4 + off_; \
            ((unsigned*)Bh[BUF])[ui_] = (unsigned)h0_ | ((unsigned)h1_ << 16); \
            ((unsigned*)Bl[BUF])[ui_] = (unsigned)l0_ | ((unsigned)l1_ << 16); \
        } } while(0)

    // prologue: fetch step 0, stage B(0) into buf 0
    LOADB(0);
    LOADA(0);
    WRITEB(0);

    for (int t = 0; t < ns; ++t){
        __syncthreads();                       // B(t) LDS writes visible to all waves
        CVTA();                                // A(t) raw -> frags (waits its vmcnt)
        bool more = (t+1 < ns);
        if (more){ LOADA(t+1); LOADB(t+1); }   // issue next-step global loads early
        int bi = t & 1;
        #pragma unroll
        for (int ni = 0; ni < 10; ++ni){
            bf16x8 bh = *(const bf16x8*)&Bh[bi][(quad*160 + ni*16 + col)*8];
            bf16x8 bl = *(const bf16x8*)&Bl[bi][(quad*160 + ni*16 + col)*8];
            acc[ni] = __builtin_amdgcn_mfma_f32_16x16x32_bf16(ah, bh, acc[ni], 0,0,0);
            acc[ni] = __builtin_amdgcn_mfma_f32_16x16x32_bf16(al, bh, acc[ni], 0,0,0);
            acc[ni] = __builtin_amdgcn_mfma_f32_16x16x32_bf16(ah, bl, acc[ni], 0,0,0);
        }
        if (more) WRITEB((t+1)&1);             // waits B(t+1) vmcnt; other buffer
    }

#undef LOADA
#undef LOADB
#undef CVTA
#undef WRITEB

    #pragma unroll
    for (int ni = 0; ni < 10; ++ni)
        #pragma unroll
        for (int r = 0; r < 4; ++r)
            hpart[hbase + (long)(w*16 + quad*4 + r)*160 + ni*16 + col] = acc[ni][r];
}

// ------------------------------------------------- reduce split-K partials v2
// grid (75, 4): y-chunk sums 64 z's -> 300 blocks. k_final sums the 4 slices.
__global__ void k_red(const float* __restrict__ hpart, float* __restrict__ hpre4){
    int t = blockIdx.x*256 + threadIdx.x;
    if (t >= 128*HID_) return;
    int y = blockIdx.y;
    int b = t / HID_, n = t % HID_;
    float s = 0.0f;
    int z0 = y*64;
    for (int z = z0; z < z0+64; ++z)
        s += hpart[(long)z*(128*160) + (long)b*160 + n];
    hpre4[(long)y*(128*HID_) + t] = s;
}

// ------------------------------------------------- tanh + layer2 + log_softmax
__global__ void k_final(const float* __restrict__ hpre4, const float* __restrict__ b1,
        const float* __restrict__ W2, const float* __restrict__ b2,
        float* __restrict__ out){
    int b = threadIdx.x;
    if (b >= 128) return;
    float z0 = b2[0], z1 = b2[1];
    for (int n = 0; n < HID_; ++n){
        int idx = b*HID_ + n;
        float hp = hpre4[idx] + hpre4[19200 + idx] + hpre4[38400 + idx] + hpre4[57600 + idx];
        float hv = fast_tanh(hp + b1[n]);
        z0 = fmaf(hv, W2[n*2+0], z0);
        z1 = fmaf(hv, W2[n*2+1], z1);
    }
    float m = fmaxf(z0, z1);
    float lse = m + logf(expf(z0-m) + expf(z1-m));
    out[b*2+0] = z0 - lse;
    out[b*2+1] = z1 - lse;
}

extern "C" void kernel_launch(void* const* d_in, const int* in_sizes, int n_in,
                              void* d_out, int out_size, void* d_ws, size_t ws_size,
                              hipStream_t stream){
    const int*   sa  = (const int*)d_in[0];
    const int*   sb  = (const int*)d_in[1];
    const float* emb = (const float*)d_in[2];
    const float* hw1 = (const float*)d_in[3];
    const float* hb1 = (const float*)d_in[4];
    const float* pw1 = (const float*)d_in[5];
    const float* pb1 = (const float*)d_in[6];
    const float* hw2 = (const float*)d_in[7];
    const float* hb2 = (const float*)d_in[8];
    const float* pw2 = (const float*)d_in[9];
    const float* pb2 = (const float*)d_in[10];
    const float* hw3 = (const float*)d_in[11];
    const float* hb3 = (const float*)d_in[12];
    const float* pw3 = (const float*)d_in[13];
    const float* pb3 = (const float*)d_in[14];
    const float* W1  = (const float*)d_in[15];
    const float* b1  = (const float*)d_in[16];
    const float* W2  = (const float*)d_in[17];
    const float* b2  = (const float*)d_in[18];
    float* out = (float*)d_out;

    float* ws    = (float*)d_ws;
    float* S     = ws;                       // 300*16384      = 4,915,200
    float* APOOL = S + 4915200;              // 2*3*3*128*300  =   691,200
    float* AINF  = APOOL + 691200;           // 2*3*128        =       768
    float* PPOOL = AINF + 768;               // 2*3*2*128*6000 = 9,216,000
    float* FEAT  = PPOOL + 9216000;          // 128*44428      = 5,686,784 (padded rows)
    float* HPRE  = FEAT + 5686784;           // 4*128*150      =    76,800
    // time-multiplexed overlays:
    //  - SbfK (10*16448*32 bf16 = 2,631,680 floats) + Wbf overlay PPOOL until hconv9
    //    finishes (k_sfeat/pdim then overwrites)
    //  - HPART (256*128*160 = 5,242,880 floats) overlays S..AINF (dead by mlp1)
    unsigned short* SBFK = (unsigned short*)PPOOL;
    unsigned short* WBF  = (unsigned short*)(PPOOL + 2631680);
    float* HPART = ws;

    k_prep<<<2977, 256, 0, stream>>>(sa, sb, emb, hw1, hw2, hw3, S, SBFK, WBF);
    k_hconv9<<<1536, 256, 0, stream>>>(SBFK, WBF, hb1, hb2, hb3, APOOL);
    k_sfeat<<<6256, 256, 0, stream>>>(S, pw1,pb1, pw2,pb2, pw3,pb3, PPOOL, AINF);
    k_feat<<<1634, 256, 0, stream>>>(APOOL, AINF, PPOOL, FEAT);
    k_mlp1<<<dim3(ZB_), 512, 0, stream>>>(FEAT, W1, HPART);
    k_red<<<dim3(75, 4), 256, 0, stream>>>(HPART, HPRE);
    k_final<<<1, 128, 0, stream>>>(HPRE, b1, W2, b2, out);
}

// Round 10
// 305.120 us; speedup vs baseline: 1.2495x; 1.0414x over previous
//
#include <hip/hip_runtime.h>
#include <math.h>

#define B_    128
#define L_    64
#define C_    300
#define NH_   300
#define K_    20
#define HID_  150
#define N_    (B_*L_)       // 8192
#define N2_   (2*N_)        // 16384
#define NFEAT_ 44427
#define FSTRIDE_ 44428      // padded row stride (16B-aligned rows for float4 loads)
#define ZB_   256           // split-K blocks for mlp1 (1 per CU)
#define KST_  1389          // ceil(NFEAT/32) k-steps
#define KCB_  6             // ceil(KST/ZB) k-steps per block
#define CP_   320           // padded C for bf16 GEMM (mult of 32)
#define NROWS_ 16448        // 257*64: N2_ + pad rows (staging window reads up to +81)
#define PLSZ_ 102400        // weight plane size = 10*CP_*32

typedef __attribute__((ext_vector_type(8))) short bf16x8;
typedef __attribute__((ext_vector_type(4))) float f32x4;

__device__ __forceinline__ float fast_tanh(float x){
    float e = __expf(2.0f*x);
    return 1.0f - 2.0f/(e + 1.0f);
}

__device__ __forceinline__ unsigned short f2bf(float x){
    union { float f; unsigned u; } a; a.f = x;
    unsigned r = a.u + 0x7FFFu + ((a.u >> 16) & 1u);   // RNE
    return (unsigned short)(r >> 16);
}

__device__ __forceinline__ float bf2f(unsigned short h){
    union { unsigned u; float f; } a; a.u = ((unsigned)h) << 16;
    return a.f;
}

// async global->LDS DMA, 16B/lane; lds dest must be wave-uniform base (+lane*16)
__device__ __forceinline__ void gld16(const void* g, void* l){
    __builtin_amdgcn_global_load_lds(
        (__attribute__((address_space(1))) void*)(g),
        (__attribute__((address_space(3))) void*)(l),
        16, 0, 0);
}

// ------------------------------------------------- fused prep: embed | embedT | wprep
// bid [0,320): S[c, s*N+b*64+l] = emb[tok][c]  (64 n-blocks x 5 c-chunks)
// bid [320,577): K-chunk-major bf16 SbfK[kc][n][32]
// bid [577,2977): K-chunk-major bf16 weights WBF[plane][kc][o][32]
__global__ __launch_bounds__(256) void k_prep(const int* __restrict__ sa,
        const int* __restrict__ sb, const float* __restrict__ emb,
        const float* __restrict__ hw1, const float* __restrict__ hw2,
        const float* __restrict__ hw3, float* __restrict__ S,
        unsigned short* __restrict__ sbfK, unsigned short* __restrict__ wbf){
    int bid = blockIdx.x;
    if (bid < 320){
        int n = (bid & 63)*256 + threadIdx.x;      // 0..16383
        int s = n >> 13;
        int nl = n & (N_-1);
        int tok = s ? sb[nl] : sa[nl];
        const float* row = emb + (long)tok * C_;
        int c0 = (bid >> 6) * 60;
        const float4* r4 = (const float4*)(row + c0);
        #pragma unroll
        for (int i = 0; i < 15; ++i){
            float4 f = r4[i];
            long c = c0 + i*4;
            S[c*N2_ + n]     = f.x;
            S[(c+1)*N2_ + n] = f.y;
            S[(c+2)*N2_ + n] = f.z;
            S[(c+3)*N2_ + n] = f.w;
        }
    } else if (bid < 577){
        int bx = bid - 320;
        int w = threadIdx.x >> 6, lane = threadIdx.x & 63;
        for (int i = 0; i < 16; ++i){
            long n = (long)bx*64 + w*16 + i;
            if (n >= NROWS_) return;
            bool pad = (n >= N2_);
            int tok = 0;
            if (!pad) tok = (n >= N_) ? sb[n - N_] : sa[n];
            const float4* er = (const float4*)(emb + (long)tok * C_);
            #pragma unroll
            for (int p = 0; p < 2; ++p){
                int c4 = p*64 + lane;            // float4 index, c = 4*c4
                if (c4 >= CP_/4) continue;
                ushort4 v = {0,0,0,0};
                if (!pad && c4 < 75){
                    float4 f = er[c4];
                    v.x = f2bf(f.x); v.y = f2bf(f.y); v.z = f2bf(f.z); v.w = f2bf(f.w);
                }
                ((ushort4*)(sbfK + (long)(c4 >> 3)*(NROWS_*32) + n*32))[c4 & 7] = v;
            }
        }
    } else {
        int idx = (bid - 577)*256 + threadIdx.x;   // < 614400
        int p = idx / PLSZ_, r = idx % PLSZ_;
        int kc = r / 10240, r2 = r % 10240;
        int o = r2 / 32, ii = r2 % 32;
        int c = kc*32 + ii;
        int WS, j; const float* hw;
        if (p == 0){ WS = 1; j = 0; hw = hw1; }
        else if (p < 3){ WS = 2; j = p - 1; hw = hw2; }
        else { WS = 3; j = p - 3; hw = hw3; }
        float v = (o < NH_ && c < C_) ? hw[((long)o*C_ + c)*WS + j] : 0.0f;
        wbf[idx] = f2bf(v);
    }
}

// ------------------------------------------------- fused conv: hconv | pdim | inf
// Heterogeneous launch, 7792 blocks, 1:4 interleave so every CU holds a blend of
// MFMA/latency-bound hconv blocks and VALU-bound pdim blocks (complementary pipes;
// serial they cost ~64+~33us). Block-slot map: g<7680: slot=g%5 (0 -> hconv work
// g/5, else other o=(g/5)*4+slot-1); g>=7680 -> other o=6144+(g-7680).
// other o<6000 -> pdim, else inf (o-6000).
// hconv: round-7 measured-best config (LDS 40448, separate P, 4 blocks/CU — the
// round-8 P-alias/5-blocks variant REGRESSED 54->64us, L2 dilution). XCD swizzle
// re-derived for strided launch: block 5*id sits on XCD (5*id)&7; 5 invertible
// mod 8 -> work = ((5*id)&7)*192 + (id>>3) is bijective on [0,1536).
__global__ __launch_bounds__(256) void k_conv(const unsigned short* __restrict__ sbfK,
        const unsigned short* __restrict__ wbf,
        const float* __restrict__ hb1, const float* __restrict__ hb2,
        const float* __restrict__ hb3, float* __restrict__ apool,
        const float* __restrict__ S,
        const float* __restrict__ pw1, const float* __restrict__ pb1,
        const float* __restrict__ pw2, const float* __restrict__ pb2,
        const float* __restrict__ pw3, const float* __restrict__ pb3,
        float* __restrict__ ppool, float* __restrict__ ainf){
    __shared__ __align__(16) unsigned short ALB[2][320*8];      // 5120 B per buf
    __shared__ __align__(16) unsigned short BLB[2][640*8];      // 10240 B per buf
    __shared__ float P[5][160][3];
    __shared__ float red[3][4];

    int g = blockIdx.x;
    int kind, id;
    if (g < 7680){
        int slot = g % 5, grp = g / 5;
        if (slot == 0){ kind = 0; id = grp; }
        else { int o = grp*4 + (slot - 1);
               if (o < 6000){ kind = 1; id = o; } else { kind = 2; id = o - 6000; } }
    } else {
        kind = 2; id = 144 + (g - 7680);            // o = 6144.. -> inf 144..255
    }
    int tid = threadIdx.x;

    if (kind == 0){
        int bid = (((5*id) & 7) * 192) + (id >> 3); // XCD-contiguous work id
        int wsi = bid % 3;  int rr0 = bid / 3;      // WS = wsi+1
        int nhalf = rr0 & 1; int sbx = rr0 >> 1;    // sbx 0..255
        const int WS = wsi + 1;
        const int Lo = 65 - WS;
        const int NC = 10*WS;                       // k-chunks (j-major, kc-minor)
        const int pbase = (WS*(WS-1))/2;            // plane base {0,1,3}
        const float* hb = (WS == 1) ? hb1 : (WS == 2) ? hb2 : hb3;

        int w = tid >> 6, lane = tid & 63, col = lane & 15, quad = lane >> 4;
        int s = sbx >> 7, b = sbx & 127;
        long row0 = (long)sbx*64;
        int mt0 = (w>>1)*2;
        int olocb = (w&1)*80 + col;
        int nbase = nhalf*160;
        f32x4 acc[2][5] = {};

        auto stage = [&](int ch, int bi){
            int j = ch/10, kc = ch - 10*j;
            const unsigned short* asrc = sbfK + (long)kc*(NROWS_*32) + (row0 + j)*32;
            const unsigned short* bsrc = wbf + (long)(pbase + j)*PLSZ_
                                             + (long)kc*(CP_*32) + (long)nbase*32;
            #pragma unroll
            for (int q = 0; q < 15; ++q){
                if ((q & 3) != w) continue;        // wave-uniform branch
                int e = q*64 + lane;
                if (q < 5){
                    int rr = e >> 2, slot2 = e & 3;
                    int qc = (slot2 ^ (rr >> 1)) & 3;
                    gld16(asrc + rr*32 + qc*8, &ALB[bi][q*64*8]);
                } else {
                    int eb = e - 320;              // 0..639
                    int o = eb >> 2, slot2 = eb & 3;
                    int qc = (slot2 ^ (o >> 1)) & 3;
                    gld16(bsrc + o*32 + qc*8, &BLB[bi][(q-5)*64*8]);
                }
            }
        };

        stage(0, 0);
        for (int ch = 0; ch < NC; ++ch){
            int cur = ch & 1;
            __syncthreads();                       // drains chunk ch's loads
            if (ch+1 < NC) stage(ch+1, cur^1);
            int ra0 = mt0*16 + col;
            int ra1 = ra0 + 16;
            bf16x8 a0 = *(const bf16x8*)&ALB[cur][(ra0*4 + ((quad ^ (ra0>>1)) & 3))*8];
            bf16x8 a1 = *(const bf16x8*)&ALB[cur][(ra1*4 + ((quad ^ (ra1>>1)) & 3))*8];
            #pragma unroll
            for (int ni = 0; ni < 5; ++ni){
                int o = olocb + ni*16;
                bf16x8 bfr = *(const bf16x8*)&BLB[cur][(o*4 + ((quad ^ (o>>1)) & 3))*8];
                acc[0][ni] = __builtin_amdgcn_mfma_f32_16x16x32_bf16(a0, bfr, acc[0][ni], 0,0,0);
                acc[1][ni] = __builtin_amdgcn_mfma_f32_16x16x32_bf16(a1, bfr, acc[1][ni], 0,0,0);
            }
        }

        float rmax[5], rmin[5], rsum[5];
        #pragma unroll
        for (int ni = 0; ni < 5; ++ni){
            int oloc = olocb + ni*16;
            int o = nbase + oloc;
            float bias = (o < NH_) ? hb[o] : 0.0f;
            float vmax = -1e30f, vmin = 1e30f, vsum = 0.0f;
            #pragma unroll
            for (int mi = 0; mi < 2; ++mi){
                int mt = mt0 + mi;
                #pragma unroll
                for (int r = 0; r < 4; ++r){
                    int t = mt*16 + quad*4 + r;
                    if (t < Lo){
                        float z = acc[mi][ni][r] + bias;
                        vmax = fmaxf(vmax, z); vmin = fminf(vmin, z);
                        vsum += fast_tanh(z);
                    }
                }
            }
            for (int m = 16; m < 64; m <<= 1){
                vmax = fmaxf(vmax, __shfl_xor(vmax, m, 64));
                vmin = fminf(vmin, __shfl_xor(vmin, m, 64));
                vsum += __shfl_xor(vsum, m, 64);
            }
            rmax[ni] = vmax; rmin[ni] = vmin; rsum[ni] = vsum;
            if (w < 2 && quad == 0){
                P[ni][oloc][0] = vmax; P[ni][oloc][1] = vmin; P[ni][oloc][2] = vsum;
            }
        }
        __syncthreads();
        if (w >= 2 && quad == 0){
            #pragma unroll
            for (int ni = 0; ni < 5; ++ni){
                int oloc = olocb + ni*16;
                int o = nbase + oloc;
                if (o < NH_){
                    float vmax = fmaxf(rmax[ni], P[ni][oloc][0]);
                    float vmin = fminf(rmin[ni], P[ni][oloc][1]);
                    float vsum = rsum[ni] + P[ni][oloc][2];
                    long base = ((long)((s*3 + (WS-1))*3)) * (long)(B_*NH_) + (long)b*NH_ + o;
                    apool[base]                  = fast_tanh(vmax);
                    apool[base + (long)(B_*NH_)] = -fast_tanh(vmin);
                    apool[base + 2L*(B_*NH_)]    = vsum / (float)Lo;
                }
            }
        }
    } else if (kind == 1){
        long t = (long)id*256 + tid;               // < 1,536,000
        int k = (int)(t % 20);
        long r = t / 20;
        int c = (int)(r % 300); r /= 300;
        int b = (int)(r % 128); int s = (int)(r / 128);
        const float4* rp = (const float4*)(S + (long)c*N2_ + (long)s*N_ + b*64);
        int ck = c*20 + k;
        float w10 = pw1[ck];
        float w20 = pw2[ck*2], w21 = pw2[ck*2+1];
        float w30 = pw3[ck*3], w31 = pw3[ck*3+1], w32 = pw3[ck*3+2];
        float bb1 = pb1[ck], bb2 = pb2[ck], bb3 = pb3[ck];

        float xmax=-1e30f, xmin=1e30f, mx2=-1e30f, mn2=1e30f, mx3=-1e30f, mn3=1e30f;
        float p1 = 0.0f, p2 = 0.0f;            // carries: x[base-1], x[base-2]
        float ea[16], eb[16];

#define LOADC(E, CH) do { \
        _Pragma("unroll") \
        for (int i_ = 0; i_ < 4; ++i_){ \
            float4 v_ = rp[(CH)*4 + i_]; \
            E[i_*4+0]=v_.x; E[i_*4+1]=v_.y; E[i_*4+2]=v_.z; E[i_*4+3]=v_.w; \
        } } while(0)

#define PROCC(E, FIRST) do { \
        if (!(FIRST)){ \
            float z2c_ = fmaf(w21, E[0], fmaf(w20, p1, bb2)); \
            mx2 = fmaxf(mx2, z2c_); mn2 = fminf(mn2, z2c_); \
            float z3a_ = fmaf(w32, E[0], fmaf(w31, p1, fmaf(w30, p2, bb3))); \
            mx3 = fmaxf(mx3, z3a_); mn3 = fminf(mn3, z3a_); \
            float z3b_ = fmaf(w32, E[1], fmaf(w31, E[0], fmaf(w30, p1, bb3))); \
            mx3 = fmaxf(mx3, z3b_); mn3 = fminf(mn3, z3b_); \
        } \
        _Pragma("unroll") \
        for (int i_ = 0; i_ < 16; ++i_){ \
            xmax = fmaxf(xmax, E[i_]); xmin = fminf(xmin, E[i_]); \
        } \
        _Pragma("unroll") \
        for (int i_ = 0; i_ < 15; ++i_){ \
            float z2_ = fmaf(w21, E[i_+1], fmaf(w20, E[i_], bb2)); \
            mx2 = fmaxf(mx2, z2_); mn2 = fminf(mn2, z2_); \
        } \
        _Pragma("unroll") \
        for (int i_ = 0; i_ < 14; ++i_){ \
            float z3_ = fmaf(w32, E[i_+2], fmaf(w31, E[i_+1], fmaf(w30, E[i_], bb3))); \
            mx3 = fmaxf(mx3, z3_); mn3 = fminf(mn3, z3_); \
        } \
        p2 = E[14]; p1 = E[15]; } while(0)

        LOADC(ea, 0);
        LOADC(eb, 1);
        PROCC(ea, true);
        LOADC(ea, 2);
        PROCC(eb, false);
        LOADC(eb, 3);
        PROCC(ea, false);
        PROCC(eb, false);
#undef LOADC
#undef PROCC

        float hi = (w10 >= 0.0f) ? xmax : xmin;
        float lo = (w10 >= 0.0f) ? xmin : xmax;
        float outs[6] = { fast_tanh(fmaf(w10, hi, bb1)), -fast_tanh(fmaf(w10, lo, bb1)),
                          fast_tanh(mx2), -fast_tanh(mn2),
                          fast_tanh(mx3), -fast_tanh(mn3) };
        long stride_sw = 128L*6000L;
        long off = (long)b*6000 + (long)c*20 + k;
        #pragma unroll
        for (int wsi = 0; wsi < 3; ++wsi)
            #pragma unroll
            for (int pool = 0; pool < 2; ++pool){
                long slot = (long)((s*3+wsi)*2 + pool);
                ppool[slot*stride_sw + off] = outs[wsi*2+pool];
            }
    } else {
        int s = id >> 7, b = id & 127;
        long base = (long)s*N_ + b*64;
        float vmax = -1e30f, vnmax = -1e30f, vsum = 0.f;
        for (int idx = tid; idx < C_*64; idx += 256){
            int c = idx >> 6, l = idx & 63;
            float v = S[(long)c*N2_ + base + l];
            vmax = fmaxf(vmax, v);
            vnmax = fmaxf(vnmax, -v);
            vsum += v;
        }
        for (int m = 1; m < 64; m <<= 1){
            vmax  = fmaxf(vmax,  __shfl_xor(vmax, m, 64));
            vnmax = fmaxf(vnmax, __shfl_xor(vnmax, m, 64));
            vsum += __shfl_xor(vsum, m, 64);
        }
        int w = tid >> 6;
        if ((tid & 63) == 0){ red[0][w]=vmax; red[1][w]=vnmax; red[2][w]=vsum; }
        __syncthreads();
        if (tid == 0){
            float a = fmaxf(fmaxf(red[0][0],red[0][1]),fmaxf(red[0][2],red[0][3]));
            float nn= fmaxf(fmaxf(red[1][0],red[1][1]),fmaxf(red[1][2],red[1][3]));
            float su= red[2][0]+red[2][1]+red[2][2]+red[2][3];
            ainf[(s*3+0)*128 + b] = a;
            ainf[(s*3+1)*128 + b] = nn;
            ainf[(s*3+2)*128 + b] = su / (float)(C_*64);
        }
    }
}

// ------------------------------------------------- fused feature kernel
// bid [0,864): pairs — 4 units/block. bid [864,1632): pdimfeat.
// bid [1632,1634): infeat.
__global__ __launch_bounds__(256) void k_feat(const float* __restrict__ apool,
        const float* __restrict__ ainf, const float* __restrict__ ppool,
        float* __restrict__ feat){
    __shared__ float X1[20*305];
    __shared__ float X2[20*305];
    int bid = blockIdx.x;
    int tid = threadIdx.x;
    if (bid < 864){
        int w = tid >> 6, lane = tid & 63;
        int u = bid*4 + w;                     // 0..3455
        int b = u / 27, rest = u - 27*b;
        int p = rest / 9, q = rest - 9*p;
        int w1 = q / 3, w2 = q % 3;
        const float* x1 = apool + ((long)((0*3 + w1)*3 + p))*(long)(B_*NH_) + (long)b*NH_;
        const float* x2 = apool + ((long)((1*3 + w2)*3 + p))*(long)(B_*NH_) + (long)b*NH_;
        float dot=0, n1=0, n2=0, d2=0;
        long fb = (long)b*FSTRIDE_;
        long vbase = 24 + (long)p*2721 + (long)q*302;
        for (int i = lane; i < NH_; i += 64){
            float a = x1[i], bb = x2[i];
            dot = fmaf(a, bb, dot); n1 = fmaf(a, a, n1); n2 = fmaf(bb, bb, n2);
            float dd = a - bb + 1e-6f;
            d2 = fmaf(dd, dd, d2);
            feat[fb + vbase + 2 + i] = fabsf(a - bb);
        }
        for (int m = 1; m < 64; m <<= 1){
            dot += __shfl_xor(dot, m, 64);
            n1  += __shfl_xor(n1, m, 64);
            n2  += __shfl_xor(n2, m, 64);
            d2  += __shfl_xor(d2, m, 64);
        }
        if (lane == 0){
            float cosv = dot / fmaxf(sqrtf(n1)*sqrtf(n2), 1e-8f);
            float distv = sqrtf(d2);
            feat[fb + vbase + 0] = cosv;
            feat[fb + vbase + 1] = distv;
            if (w1 == w2){
                feat[fb + p*8 + w1*2 + 0] = cosv;
                feat[fb + p*8 + w1*2 + 1] = distv;
            }
        }
    } else if (bid < 1632){
        int r = bid - 864;
        int b = r & 127, pw = r >> 7;
        int pool = pw / 3, wsi = pw % 3;
        long stride_sw = 128L*6000L;
        const float* x1 = ppool + (long)((0*3+wsi)*2+pool)*stride_sw + (long)b*6000;
        const float* x2 = ppool + (long)((1*3+wsi)*2+pool)*stride_sw + (long)b*6000;
        for (int idx = tid; idx < 6000; idx += 256){
            int c = idx / 20, k = idx - 20*c;
            X1[k*305 + c] = x1[idx];
            X2[k*305 + c] = x2[idx];
        }
        __syncthreads();
        int w = tid >> 6, lane = tid & 63;
        for (int k = w; k < 20; k += 4){
            float dot=0, n1=0, n2=0, d2=0;
            long fb = (long)b*FSTRIDE_ + 8187 + (long)pw*6040 + (long)k*302;
            for (int c = lane; c < C_; c += 64){
                float a = X1[k*305 + c], bb = X2[k*305 + c];
                dot = fmaf(a, bb, dot); n1 = fmaf(a, a, n1); n2 = fmaf(bb, bb, n2);
                float dd = a - bb + 1e-6f;
                d2 = fmaf(dd, dd, d2);
                feat[fb + 2 + c] = fabsf(a - bb);
            }
            for (int m = 1; m < 64; m <<= 1){
                dot += __shfl_xor(dot, m, 64);
                n1  += __shfl_xor(n1, m, 64);
                n2  += __shfl_xor(n2, m, 64);
                d2  += __shfl_xor(d2, m, 64);
            }
            if (lane == 0){
                feat[fb + 0] = dot / fmaxf(sqrtf(n1)*sqrtf(n2), 1e-8f);
                feat[fb + 1] = sqrtf(d2);
            }
        }
    } else {
        int t = (bid - 1632)*256 + tid;
        if (t >= 384) return;
        int b = t & 127, p = t >> 7;
        float x1 = ainf[(0*3+p)*128 + b];
        float x2 = ainf[(1*3+p)*128 + b];
        float cosv = (x1*x2) / fmaxf(fabsf(x1)*fabsf(x2), 1e-8f);
        float distv = fabsf(x1 - x2 + 1e-6f);
        long fb = (long)b*FSTRIDE_;
        feat[fb + p*8 + 6] = cosv;
        feat[fb + p*8 + 7] = distv;
        long vb = 24 + (long)p*2721 + 9L*302;
        feat[fb + vb + 0] = cosv;
        feat[fb + vb + 1] = distv;
        feat[fb + vb + 2] = fabsf(x1 - x2);
    }
}

// ------------------------------------------------- MLP layer 1: MFMA split-K v6
__global__ __launch_bounds__(512) void k_mlp1(const float* __restrict__ feat,
        const float* __restrict__ W1, float* __restrict__ hpart){
    __shared__ __align__(16) unsigned short Bh[2][5120];   // 4 k-octets * 160 n * 8
    __shared__ __align__(16) unsigned short Bl[2][5120];
    int tid = threadIdx.x;
    int w = tid >> 6, lane = tid & 63, col = lane & 15, quad = lane >> 4;
    int z = blockIdx.x;
    int t0 = z * KCB_;
    int ns = KST_ - t0; if (ns > KCB_) ns = KCB_;
    long hbase = (long)z * (128*160);
    int mrow = w*16 + col;                       // wave's m-tile row for A-frag

    if (ns <= 0){
        #pragma unroll
        for (int ni = 0; ni < 10; ++ni)
            #pragma unroll
            for (int r = 0; r < 4; ++r)
                hpart[hbase + (long)(w*16 + quad*4 + r)*160 + ni*16 + col] = 0.0f;
        return;
    }

    // B staging assignment: 2560 (k-pair, n) cells, 5 per thread (constant per step)
    int k2a[5], na[5];
    #pragma unroll
    for (int i = 0; i < 5; ++i){
        int p = i*512 + tid;
        k2a[i] = p / 160; na[i] = p - 160*k2a[i];   // k2 in 0..15 (k = 2*k2), n in 0..159
    }

    const float* arow = feat + (long)mrow * FSTRIDE_;
    float af[8];                 // raw A dwords for current/next step
    float bf0[5], bf1[5];        // raw B pair values
    bf16x8 ah, al;               // current A frags
    f32x4 acc[10] = {};

#define LOADA(STEP) do { \
        int ks_ = t0 + (STEP); \
        int kb_ = ks_*32 + quad*8; \
        if (ks_ < 1388){ \
            float4 f0_ = *(const float4*)(arow + kb_); \
            float4 f1_ = *(const float4*)(arow + kb_ + 4); \
            af[0]=f0_.x; af[1]=f0_.y; af[2]=f0_.z; af[3]=f0_.w; \
            af[4]=f1_.x; af[5]=f1_.y; af[6]=f1_.z; af[7]=f1_.w; \
        } else { \
            _Pragma("unroll") \
            for (int j_ = 0; j_ < 8; ++j_){ \
                int k_ = kb_ + j_; \
                af[j_] = (k_ < NFEAT_) ? arow[k_] : 0.0f; \
            } \
        } } while(0)

#define LOADB(STEP) do { \
        int kb_ = (t0 + (STEP))*32; \
        _Pragma("unroll") \
        for (int i_ = 0; i_ < 5; ++i_){ \
            int k_ = kb_ + 2*k2a[i_]; int n_ = na[i_]; \
            bf0[i_] = (k_   < NFEAT_ && n_ < HID_) ? W1[(long)k_*HID_ + n_]     : 0.0f; \
            bf1[i_] = (k_+1 < NFEAT_ && n_ < HID_) ? W1[(long)(k_+1)*HID_ + n_] : 0.0f; \
        } } while(0)

#define CVTA() do { \
        _Pragma("unroll") \
        for (int j_ = 0; j_ < 8; ++j_){ \
            unsigned short h_ = f2bf(af[j_]); \
            unsigned short l_ = f2bf(af[j_] - bf2f(h_)); \
            ah[j_] = (short)h_; al[j_] = (short)l_; \
        } } while(0)

#define WRITEB(BUF) do { \
        _Pragma("unroll") \
        for (int i_ = 0; i_ < 5; ++i_){ \
            int k2_ = k2a[i_]; int n_ = na[i_]; \
            int q_ = k2_ >> 2, off_ = k2_ & 3; \
            unsigned short h0_ = f2bf(bf0[i_]); \
            unsigned short l0_ = f2bf(bf0[i_] - bf2f(h0_)); \
            unsigned short h1_ = f2bf(bf1[i_]); \
            unsigned short l1_ = f2bf(bf1[i_] - bf2f(h1_)); \
            int ui_ = (q_*160 + n_)*4 + off_; \
            ((unsigned*)Bh[BUF])[ui_] = (unsigned)h0_ | ((unsigned)h1_ << 16); \
            ((unsigned*)Bl[BUF])[ui_] = (unsigned)l0_ | ((unsigned)l1_ << 16); \
        } } while(0)

    // prologue: fetch step 0, stage B(0) into buf 0
    LOADB(0);
    LOADA(0);
    WRITEB(0);

    for (int t = 0; t < ns; ++t){
        __syncthreads();                       // B(t) LDS writes visible to all waves
        CVTA();                                // A(t) raw -> frags (waits its vmcnt)
        bool more = (t+1 < ns);
        if (more){ LOADA(t+1); LOADB(t+1); }   // issue next-step global loads early
        int bi = t & 1;
        #pragma unroll
        for (int ni = 0; ni < 10; ++ni){
            bf16x8 bh = *(const bf16x8*)&Bh[bi][(quad*160 + ni*16 + col)*8];
            bf16x8 bl = *(const bf16x8*)&Bl[bi][(quad*160 + ni*16 + col)*8];
            acc[ni] = __builtin_amdgcn_mfma_f32_16x16x32_bf16(ah, bh, acc[ni], 0,0,0);
            acc[ni] = __builtin_amdgcn_mfma_f32_16x16x32_bf16(al, bh, acc[ni], 0,0,0);
            acc[ni] = __builtin_amdgcn_mfma_f32_16x16x32_bf16(ah, bl, acc[ni], 0,0,0);
        }
        if (more) WRITEB((t+1)&1);             // waits B(t+1) vmcnt; other buffer
    }

#undef LOADA
#undef LOADB
#undef CVTA
#undef WRITEB

    #pragma unroll
    for (int ni = 0; ni < 10; ++ni)
        #pragma unroll
        for (int r = 0; r < 4; ++r)
            hpart[hbase + (long)(w*16 + quad*4 + r)*160 + ni*16 + col] = acc[ni][r];
}

// ------------------------------------------------- reduce split-K partials v2
// grid (75, 4): y-chunk sums 64 z's -> 300 blocks. k_final sums the 4 slices.
__global__ void k_red(const float* __restrict__ hpart, float* __restrict__ hpre4){
    int t = blockIdx.x*256 + threadIdx.x;
    if (t >= 128*HID_) return;
    int y = blockIdx.y;
    int b = t / HID_, n = t % HID_;
    float s = 0.0f;
    int z0 = y*64;
    for (int z = z0; z < z0+64; ++z)
        s += hpart[(long)z*(128*160) + (long)b*160 + n];
    hpre4[(long)y*(128*HID_) + t] = s;
}

// ------------------------------------------------- tanh + layer2 + log_softmax
__global__ void k_final(const float* __restrict__ hpre4, const float* __restrict__ b1,
        const float* __restrict__ W2, const float* __restrict__ b2,
        float* __restrict__ out){
    int b = threadIdx.x;
    if (b >= 128) return;
    float z0 = b2[0], z1 = b2[1];
    for (int n = 0; n < HID_; ++n){
        int idx = b*HID_ + n;
        float hp = hpre4[idx] + hpre4[19200 + idx] + hpre4[38400 + idx] + hpre4[57600 + idx];
        float hv = fast_tanh(hp + b1[n]);
        z0 = fmaf(hv, W2[n*2+0], z0);
        z1 = fmaf(hv, W2[n*2+1], z1);
    }
    float m = fmaxf(z0, z1);
    float lse = m + logf(expf(z0-m) + expf(z1-m));
    out[b*2+0] = z0 - lse;
    out[b*2+1] = z1 - lse;
}

extern "C" void kernel_launch(void* const* d_in, const int* in_sizes, int n_in,
                              void* d_out, int out_size, void* d_ws, size_t ws_size,
                              hipStream_t stream){
    const int*   sa  = (const int*)d_in[0];
    const int*   sb  = (const int*)d_in[1];
    const float* emb = (const float*)d_in[2];
    const float* hw1 = (const float*)d_in[3];
    const float* hb1 = (const float*)d_in[4];
    const float* pw1 = (const float*)d_in[5];
    const float* pb1 = (const float*)d_in[6];
    const float* hw2 = (const float*)d_in[7];
    const float* hb2 = (const float*)d_in[8];
    const float* pw2 = (const float*)d_in[9];
    const float* pb2 = (const float*)d_in[10];
    const float* hw3 = (const float*)d_in[11];
    const float* hb3 = (const float*)d_in[12];
    const float* pw3 = (const float*)d_in[13];
    const float* pb3 = (const float*)d_in[14];
    const float* W1  = (const float*)d_in[15];
    const float* b1  = (const float*)d_in[16];
    const float* W2  = (const float*)d_in[17];
    const float* b2  = (const float*)d_in[18];
    float* out = (float*)d_out;

    float* ws    = (float*)d_ws;
    float* S     = ws;                       // 300*16384      = 4,915,200
    float* APOOL = S + 4915200;              // 2*3*3*128*300  =   691,200
    float* AINF  = APOOL + 691200;           // 2*3*128        =       768
    float* PPOOL = AINF + 768;               // 2*3*2*128*6000 = 9,216,000
    float* FEAT  = PPOOL + 9216000;          // 128*44428      = 5,686,784 (padded rows)
    float* HPRE  = FEAT + 5686784;           // 4*128*150      =    76,800
    // SBFK/WBF now DEDICATED (no PPOOL overlay) so k_conv's hconv and pdim/inf
    // parts are truly independent and can share one launch:
    unsigned short* SBFK = (unsigned short*)(HPRE + 76800);   // 10*16448*32 ushorts
    unsigned short* WBF  = SBFK + 10*NROWS_*32;               // 614,400 ushorts
    // HPART (256*128*160 = 5,242,880 floats) overlays S..APOOL (dead by mlp1)
    float* HPART = ws;

    k_prep<<<2977, 256, 0, stream>>>(sa, sb, emb, hw1, hw2, hw3, S, SBFK, WBF);
    k_conv<<<7792, 256, 0, stream>>>(SBFK, WBF, hb1, hb2, hb3, APOOL,
                                     S, pw1,pb1, pw2,pb2, pw3,pb3, PPOOL, AINF);
    k_feat<<<1634, 256, 0, stream>>>(APOOL, AINF, PPOOL, FEAT);
    k_mlp1<<<dim3(ZB_), 512, 0, stream>>>(FEAT, W1, HPART);
    k_red<<<dim3(75, 4), 256, 0, stream>>>(HPART, HPRE);
    k_final<<<1, 128, 0, stream>>>(HPRE, b1, W2, b2, out);
}

// Round 11
// 276.001 us; speedup vs baseline: 1.3814x; 1.1055x over previous
//
#include <hip/hip_runtime.h>
#include <math.h>

#define B_    128
#define L_    64
#define C_    300
#define NH_   300
#define K_    20
#define HID_  150
#define N_    (B_*L_)       // 8192
#define N2_   (2*N_)        // 16384
#define NFEAT_ 44427
#define FSTRIDE_ 44428      // padded row stride (16B-aligned rows for float4 loads)
#define ZB_   256           // split-K blocks for mlp1 (1 per CU)
#define KST_  1389          // ceil(NFEAT/32) k-steps
#define KCB_  6             // ceil(KST/ZB) k-steps per block
#define CP_   320           // padded C for bf16 GEMM (mult of 32)
#define NROWS_ 16448        // 257*64: N2_ + pad rows (staging window reads up to +81)
#define PLSZ_ 102400        // weight plane size = 10*CP_*32

typedef __attribute__((ext_vector_type(8))) short bf16x8;
typedef __attribute__((ext_vector_type(4))) float f32x4;

__device__ __forceinline__ float fast_tanh(float x){
    float e = __expf(2.0f*x);
    return 1.0f - 2.0f/(e + 1.0f);
}

__device__ __forceinline__ unsigned short f2bf(float x){
    union { float f; unsigned u; } a; a.f = x;
    unsigned r = a.u + 0x7FFFu + ((a.u >> 16) & 1u);   // RNE
    return (unsigned short)(r >> 16);
}

__device__ __forceinline__ float bf2f(unsigned short h){
    union { unsigned u; float f; } a; a.u = ((unsigned)h) << 16;
    return a.f;
}

// async global->LDS DMA, 16B/lane; lds dest must be wave-uniform base (+lane*16)
__device__ __forceinline__ void gld16(const void* g, void* l){
    __builtin_amdgcn_global_load_lds(
        (__attribute__((address_space(1))) void*)(g),
        (__attribute__((address_space(3))) void*)(l),
        16, 0, 0);
}

// ------------------------------------------------- fused prep: embed | embedT | wprep
// bid [0,320): S[c, s*N+b*64+l] = emb[tok][c]  (64 n-blocks x 5 c-chunks)
// bid [320,577): K-chunk-major bf16 SbfK[kc][n][32]
// bid [577,2977): K-chunk-major bf16 weights WBF[plane][kc][o][32]
__global__ __launch_bounds__(256) void k_prep(const int* __restrict__ sa,
        const int* __restrict__ sb, const float* __restrict__ emb,
        const float* __restrict__ hw1, const float* __restrict__ hw2,
        const float* __restrict__ hw3, float* __restrict__ S,
        unsigned short* __restrict__ sbfK, unsigned short* __restrict__ wbf){
    int bid = blockIdx.x;
    if (bid < 320){
        int n = (bid & 63)*256 + threadIdx.x;      // 0..16383
        int s = n >> 13;
        int nl = n & (N_-1);
        int tok = s ? sb[nl] : sa[nl];
        const float* row = emb + (long)tok * C_;
        int c0 = (bid >> 6) * 60;
        const float4* r4 = (const float4*)(row + c0);
        #pragma unroll
        for (int i = 0; i < 15; ++i){
            float4 f = r4[i];
            long c = c0 + i*4;
            S[c*N2_ + n]     = f.x;
            S[(c+1)*N2_ + n] = f.y;
            S[(c+2)*N2_ + n] = f.z;
            S[(c+3)*N2_ + n] = f.w;
        }
    } else if (bid < 577){
        int bx = bid - 320;
        int w = threadIdx.x >> 6, lane = threadIdx.x & 63;
        for (int i = 0; i < 16; ++i){
            long n = (long)bx*64 + w*16 + i;
            if (n >= NROWS_) return;
            bool pad = (n >= N2_);
            int tok = 0;
            if (!pad) tok = (n >= N_) ? sb[n - N_] : sa[n];
            const float4* er = (const float4*)(emb + (long)tok * C_);
            #pragma unroll
            for (int p = 0; p < 2; ++p){
                int c4 = p*64 + lane;            // float4 index, c = 4*c4
                if (c4 >= CP_/4) continue;
                ushort4 v = {0,0,0,0};
                if (!pad && c4 < 75){
                    float4 f = er[c4];
                    v.x = f2bf(f.x); v.y = f2bf(f.y); v.z = f2bf(f.z); v.w = f2bf(f.w);
                }
                ((ushort4*)(sbfK + (long)(c4 >> 3)*(NROWS_*32) + n*32))[c4 & 7] = v;
            }
        }
    } else {
        int idx = (bid - 577)*256 + threadIdx.x;   // < 614400
        int p = idx / PLSZ_, r = idx % PLSZ_;
        int kc = r / 10240, r2 = r % 10240;
        int o = r2 / 32, ii = r2 % 32;
        int c = kc*32 + ii;
        int WS, j; const float* hw;
        if (p == 0){ WS = 1; j = 0; hw = hw1; }
        else if (p < 3){ WS = 2; j = p - 1; hw = hw2; }
        else { WS = 3; j = p - 3; hw = hw3; }
        float v = (o < NH_ && c < C_) ? hw[((long)o*C_ + c)*WS + j] : 0.0f;
        wbf[idx] = f2bf(v);
    }
}

// ------------------------------------------------- fused conv: hconv | pdim | inf
// Heterogeneous launch, 7792 blocks, 1:4 interleave. v2: P reduction buffer
// ALIASED into staging buffer 0 (last chunk parity = 1 for all WS; P region is
// inside buffer 0, read only in epilogue) -> LDS 40448->30720B -> 5 blocks/CU.
// Round-9's regression of this alias was in the ALL-hconv kernel (5 concurrent
// hconv/CU diluted per-XCD L2); here hconv is 1/5 of blocks so the extra slot
// goes to a pdim block, restoring pdim's standalone occupancy.
__global__ __launch_bounds__(256) void k_conv(const unsigned short* __restrict__ sbfK,
        const unsigned short* __restrict__ wbf,
        const float* __restrict__ hb1, const float* __restrict__ hb2,
        const float* __restrict__ hb3, float* __restrict__ apool,
        const float* __restrict__ S,
        const float* __restrict__ pw1, const float* __restrict__ pb1,
        const float* __restrict__ pw2, const float* __restrict__ pb2,
        const float* __restrict__ pw3, const float* __restrict__ pb3,
        float* __restrict__ ppool, float* __restrict__ ainf){
    __shared__ __align__(16) unsigned char LDSU[2][15360];  // per buf: A 5120 | B 10240
    int g = blockIdx.x;
    int kind, id;
    if (g < 7680){
        int slot = g % 5, grp = g / 5;
        if (slot == 0){ kind = 0; id = grp; }
        else { int o = grp*4 + (slot - 1);
               if (o < 6000){ kind = 1; id = o; } else { kind = 2; id = o - 6000; } }
    } else {
        kind = 2; id = 144 + (g - 7680);            // o = 6144.. -> inf 144..255
    }
    int tid = threadIdx.x;

    if (kind == 0){
        int bid = (((5*id) & 7) * 192) + (id >> 3); // XCD-contiguous work id
        int wsi = bid % 3;  int rr0 = bid / 3;      // WS = wsi+1
        int nhalf = rr0 & 1; int sbx = rr0 >> 1;    // sbx 0..255
        const int WS = wsi + 1;
        const int Lo = 65 - WS;
        const int NC = 10*WS;                       // k-chunks (j-major, kc-minor)
        const int pbase = (WS*(WS-1))/2;            // plane base {0,1,3}
        const float* hb = (WS == 1) ? hb1 : (WS == 2) ? hb2 : hb3;

        int w = tid >> 6, lane = tid & 63, col = lane & 15, quad = lane >> 4;
        int s = sbx >> 7, b = sbx & 127;
        long row0 = (long)sbx*64;
        int mt0 = (w>>1)*2;
        int olocb = (w&1)*80 + col;
        int nbase = nhalf*160;
        f32x4 acc[2][5] = {};

        auto stage = [&](int ch, int bi){
            int j = ch/10, kc = ch - 10*j;
            const unsigned short* asrc = sbfK + (long)kc*(NROWS_*32) + (row0 + j)*32;
            const unsigned short* bsrc = wbf + (long)(pbase + j)*PLSZ_
                                             + (long)kc*(CP_*32) + (long)nbase*32;
            unsigned short* AL = (unsigned short*)LDSU[bi];
            unsigned short* BL = (unsigned short*)(LDSU[bi] + 5120);
            #pragma unroll
            for (int q = 0; q < 15; ++q){
                if ((q & 3) != w) continue;        // wave-uniform branch
                int e = q*64 + lane;
                if (q < 5){
                    int rr = e >> 2, slot2 = e & 3;
                    int qc = (slot2 ^ (rr >> 1)) & 3;
                    gld16(asrc + rr*32 + qc*8, AL + q*64*8);
                } else {
                    int eb = e - 320;              // 0..639
                    int o = eb >> 2, slot2 = eb & 3;
                    int qc = (slot2 ^ (o >> 1)) & 3;
                    gld16(bsrc + o*32 + qc*8, BL + (q-5)*64*8);
                }
            }
        };

        stage(0, 0);
        for (int ch = 0; ch < NC; ++ch){
            int cur = ch & 1;
            __syncthreads();                       // drains chunk ch's loads
            if (ch+1 < NC) stage(ch+1, cur^1);
            const unsigned short* AL = (const unsigned short*)LDSU[cur];
            const unsigned short* BL = (const unsigned short*)(LDSU[cur] + 5120);
            int ra0 = mt0*16 + col;
            int ra1 = ra0 + 16;
            bf16x8 a0 = *(const bf16x8*)&AL[(ra0*4 + ((quad ^ (ra0>>1)) & 3))*8];
            bf16x8 a1 = *(const bf16x8*)&AL[(ra1*4 + ((quad ^ (ra1>>1)) & 3))*8];
            #pragma unroll
            for (int ni = 0; ni < 5; ++ni){
                int o = olocb + ni*16;
                bf16x8 bfr = *(const bf16x8*)&BL[(o*4 + ((quad ^ (o>>1)) & 3))*8];
                acc[0][ni] = __builtin_amdgcn_mfma_f32_16x16x32_bf16(a0, bfr, acc[0][ni], 0,0,0);
                acc[1][ni] = __builtin_amdgcn_mfma_f32_16x16x32_bf16(a1, bfr, acc[1][ni], 0,0,0);
            }
        }

        // epilogue reduction; P aliases LDSU[0] (last chunk parity = 1 for all WS)
        float* Pf = (float*)LDSU[0];               // [5][160][3] = 9600 B < 15360
        float rmax[5], rmin[5], rsum[5];
        #pragma unroll
        for (int ni = 0; ni < 5; ++ni){
            int oloc = olocb + ni*16;
            int o = nbase + oloc;
            float bias = (o < NH_) ? hb[o] : 0.0f;
            float vmax = -1e30f, vmin = 1e30f, vsum = 0.0f;
            #pragma unroll
            for (int mi = 0; mi < 2; ++mi){
                int mt = mt0 + mi;
                #pragma unroll
                for (int r = 0; r < 4; ++r){
                    int t = mt*16 + quad*4 + r;
                    if (t < Lo){
                        float z = acc[mi][ni][r] + bias;
                        vmax = fmaxf(vmax, z); vmin = fminf(vmin, z);
                        vsum += fast_tanh(z);
                    }
                }
            }
            for (int m = 16; m < 64; m <<= 1){
                vmax = fmaxf(vmax, __shfl_xor(vmax, m, 64));
                vmin = fminf(vmin, __shfl_xor(vmin, m, 64));
                vsum += __shfl_xor(vsum, m, 64);
            }
            rmax[ni] = vmax; rmin[ni] = vmin; rsum[ni] = vsum;
            if (w < 2 && quad == 0){
                Pf[(ni*160 + oloc)*3 + 0] = vmax;
                Pf[(ni*160 + oloc)*3 + 1] = vmin;
                Pf[(ni*160 + oloc)*3 + 2] = vsum;
            }
        }
        __syncthreads();
        if (w >= 2 && quad == 0){
            #pragma unroll
            for (int ni = 0; ni < 5; ++ni){
                int oloc = olocb + ni*16;
                int o = nbase + oloc;
                if (o < NH_){
                    float vmax = fmaxf(rmax[ni], Pf[(ni*160 + oloc)*3 + 0]);
                    float vmin = fminf(rmin[ni], Pf[(ni*160 + oloc)*3 + 1]);
                    float vsum = rsum[ni] + Pf[(ni*160 + oloc)*3 + 2];
                    long base = ((long)((s*3 + (WS-1))*3)) * (long)(B_*NH_) + (long)b*NH_ + o;
                    apool[base]                  = fast_tanh(vmax);
                    apool[base + (long)(B_*NH_)] = -fast_tanh(vmin);
                    apool[base + 2L*(B_*NH_)]    = vsum / (float)Lo;
                }
            }
        }
    } else if (kind == 1){
        long t = (long)id*256 + tid;               // < 1,536,000
        int k = (int)(t % 20);
        long r = t / 20;
        int c = (int)(r % 300); r /= 300;
        int b = (int)(r % 128); int s = (int)(r / 128);
        const float4* rp = (const float4*)(S + (long)c*N2_ + (long)s*N_ + b*64);
        int ck = c*20 + k;
        float w10 = pw1[ck];
        float w20 = pw2[ck*2], w21 = pw2[ck*2+1];
        float w30 = pw3[ck*3], w31 = pw3[ck*3+1], w32 = pw3[ck*3+2];
        float bb1 = pb1[ck], bb2 = pb2[ck], bb3 = pb3[ck];

        float xmax=-1e30f, xmin=1e30f, mx2=-1e30f, mn2=1e30f, mx3=-1e30f, mn3=1e30f;
        float p1 = 0.0f, p2 = 0.0f;            // carries: x[base-1], x[base-2]
        float ea[16], eb[16];

#define LOADC(E, CH) do { \
        _Pragma("unroll") \
        for (int i_ = 0; i_ < 4; ++i_){ \
            float4 v_ = rp[(CH)*4 + i_]; \
            E[i_*4+0]=v_.x; E[i_*4+1]=v_.y; E[i_*4+2]=v_.z; E[i_*4+3]=v_.w; \
        } } while(0)

#define PROCC(E, FIRST) do { \
        if (!(FIRST)){ \
            float z2c_ = fmaf(w21, E[0], fmaf(w20, p1, bb2)); \
            mx2 = fmaxf(mx2, z2c_); mn2 = fminf(mn2, z2c_); \
            float z3a_ = fmaf(w32, E[0], fmaf(w31, p1, fmaf(w30, p2, bb3))); \
            mx3 = fmaxf(mx3, z3a_); mn3 = fminf(mn3, z3a_); \
            float z3b_ = fmaf(w32, E[1], fmaf(w31, E[0], fmaf(w30, p1, bb3))); \
            mx3 = fmaxf(mx3, z3b_); mn3 = fminf(mn3, z3b_); \
        } \
        _Pragma("unroll") \
        for (int i_ = 0; i_ < 16; ++i_){ \
            xmax = fmaxf(xmax, E[i_]); xmin = fminf(xmin, E[i_]); \
        } \
        _Pragma("unroll") \
        for (int i_ = 0; i_ < 15; ++i_){ \
            float z2_ = fmaf(w21, E[i_+1], fmaf(w20, E[i_], bb2)); \
            mx2 = fmaxf(mx2, z2_); mn2 = fminf(mn2, z2_); \
        } \
        _Pragma("unroll") \
        for (int i_ = 0; i_ < 14; ++i_){ \
            float z3_ = fmaf(w32, E[i_+2], fmaf(w31, E[i_+1], fmaf(w30, E[i_], bb3))); \
            mx3 = fmaxf(mx3, z3_); mn3 = fminf(mn3, z3_); \
        } \
        p2 = E[14]; p1 = E[15]; } while(0)

        LOADC(ea, 0);
        LOADC(eb, 1);
        PROCC(ea, true);
        LOADC(ea, 2);
        PROCC(eb, false);
        LOADC(eb, 3);
        PROCC(ea, false);
        PROCC(eb, false);
#undef LOADC
#undef PROCC

        float hi = (w10 >= 0.0f) ? xmax : xmin;
        float lo = (w10 >= 0.0f) ? xmin : xmax;
        float outs[6] = { fast_tanh(fmaf(w10, hi, bb1)), -fast_tanh(fmaf(w10, lo, bb1)),
                          fast_tanh(mx2), -fast_tanh(mn2),
                          fast_tanh(mx3), -fast_tanh(mn3) };
        long stride_sw = 128L*6000L;
        long off = (long)b*6000 + (long)c*20 + k;
        #pragma unroll
        for (int wsi = 0; wsi < 3; ++wsi)
            #pragma unroll
            for (int pool = 0; pool < 2; ++pool){
                long slot = (long)((s*3+wsi)*2 + pool);
                ppool[slot*stride_sw + off] = outs[wsi*2+pool];
            }
    } else {
        float* red = (float*)LDSU[0];              // 12 floats scratch
        int s = id >> 7, b = id & 127;
        long base = (long)s*N_ + b*64;
        float vmax = -1e30f, vnmax = -1e30f, vsum = 0.f;
        for (int idx = tid; idx < C_*64; idx += 256){
            int c = idx >> 6, l = idx & 63;
            float v = S[(long)c*N2_ + base + l];
            vmax = fmaxf(vmax, v);
            vnmax = fmaxf(vnmax, -v);
            vsum += v;
        }
        for (int m = 1; m < 64; m <<= 1){
            vmax  = fmaxf(vmax,  __shfl_xor(vmax, m, 64));
            vnmax = fmaxf(vnmax, __shfl_xor(vnmax, m, 64));
            vsum += __shfl_xor(vsum, m, 64);
        }
        int w = tid >> 6;
        if ((tid & 63) == 0){ red[0*4+w]=vmax; red[1*4+w]=vnmax; red[2*4+w]=vsum; }
        __syncthreads();
        if (tid == 0){
            float a = fmaxf(fmaxf(red[0],red[1]),fmaxf(red[2],red[3]));
            float nn= fmaxf(fmaxf(red[4],red[5]),fmaxf(red[6],red[7]));
            float su= red[8]+red[9]+red[10]+red[11];
            ainf[(s*3+0)*128 + b] = a;
            ainf[(s*3+1)*128 + b] = nn;
            ainf[(s*3+2)*128 + b] = su / (float)(C_*64);
        }
    }
}

// ------------------------------------------------- fused feature kernel v2
// bid [0,864): pairs — 4 units/block. bid [864,1632): pdimfeat, TWO-PASS k-split
//   (stage k in [0,10) then [10,20)) -> X buffers 48.8KB -> 24KB -> 6 blocks/CU;
//   pass-2 re-read of the 48KB row pair is L2-hot (just staged), HBM ~unchanged.
// bid [1632,1634): infeat.
__global__ __launch_bounds__(256) void k_feat(const float* __restrict__ apool,
        const float* __restrict__ ainf, const float* __restrict__ ppool,
        float* __restrict__ feat){
    __shared__ float X1[10*300];
    __shared__ float X2[10*300];
    int bid = blockIdx.x;
    int tid = threadIdx.x;
    if (bid < 864){
        int w = tid >> 6, lane = tid & 63;
        int u = bid*4 + w;                     // 0..3455
        int b = u / 27, rest = u - 27*b;
        int p = rest / 9, q = rest - 9*p;
        int w1 = q / 3, w2 = q % 3;
        const float* x1 = apool + ((long)((0*3 + w1)*3 + p))*(long)(B_*NH_) + (long)b*NH_;
        const float* x2 = apool + ((long)((1*3 + w2)*3 + p))*(long)(B_*NH_) + (long)b*NH_;
        float dot=0, n1=0, n2=0, d2=0;
        long fb = (long)b*FSTRIDE_;
        long vbase = 24 + (long)p*2721 + (long)q*302;
        for (int i = lane; i < NH_; i += 64){
            float a = x1[i], bb = x2[i];
            dot = fmaf(a, bb, dot); n1 = fmaf(a, a, n1); n2 = fmaf(bb, bb, n2);
            float dd = a - bb + 1e-6f;
            d2 = fmaf(dd, dd, d2);
            feat[fb + vbase + 2 + i] = fabsf(a - bb);
        }
        for (int m = 1; m < 64; m <<= 1){
            dot += __shfl_xor(dot, m, 64);
            n1  += __shfl_xor(n1, m, 64);
            n2  += __shfl_xor(n2, m, 64);
            d2  += __shfl_xor(d2, m, 64);
        }
        if (lane == 0){
            float cosv = dot / fmaxf(sqrtf(n1)*sqrtf(n2), 1e-8f);
            float distv = sqrtf(d2);
            feat[fb + vbase + 0] = cosv;
            feat[fb + vbase + 1] = distv;
            if (w1 == w2){
                feat[fb + p*8 + w1*2 + 0] = cosv;
                feat[fb + p*8 + w1*2 + 1] = distv;
            }
        }
    } else if (bid < 1632){
        int r = bid - 864;
        int b = r & 127, pw = r >> 7;
        int pool = pw / 3, wsi = pw % 3;
        long stride_sw = 128L*6000L;
        const float* x1 = ppool + (long)((0*3+wsi)*2+pool)*stride_sw + (long)b*6000;
        const float* x2 = ppool + (long)((1*3+wsi)*2+pool)*stride_sw + (long)b*6000;
        int w = tid >> 6, lane = tid & 63;
        #pragma unroll
        for (int half = 0; half < 2; ++half){
            if (half) __syncthreads();         // pass-1 reads done before overwrite
            for (int idx = tid; idx < 3000; idx += 256){
                int c = idx / 10, kk = idx - 10*c;   // k = half*10+kk
                X1[kk*300 + c] = x1[c*20 + half*10 + kk];
                X2[kk*300 + c] = x2[c*20 + half*10 + kk];
            }
            __syncthreads();
            for (int kk = w; kk < 10; kk += 4){
                int k = half*10 + kk;
                float dot=0, n1=0, n2=0, d2=0;
                long fb = (long)b*FSTRIDE_ + 8187 + (long)pw*6040 + (long)k*302;
                for (int c = lane; c < C_; c += 64){
                    float a = X1[kk*300 + c], bb = X2[kk*300 + c];
                    dot = fmaf(a, bb, dot); n1 = fmaf(a, a, n1); n2 = fmaf(bb, bb, n2);
                    float dd = a - bb + 1e-6f;
                    d2 = fmaf(dd, dd, d2);
                    feat[fb + 2 + c] = fabsf(a - bb);
                }
                for (int m = 1; m < 64; m <<= 1){
                    dot += __shfl_xor(dot, m, 64);
                    n1  += __shfl_xor(n1, m, 64);
                    n2  += __shfl_xor(n2, m, 64);
                    d2  += __shfl_xor(d2, m, 64);
                }
                if (lane == 0){
                    feat[fb + 0] = dot / fmaxf(sqrtf(n1)*sqrtf(n2), 1e-8f);
                    feat[fb + 1] = sqrtf(d2);
                }
            }
        }
    } else {
        int t = (bid - 1632)*256 + tid;
        if (t >= 384) return;
        int b = t & 127, p = t >> 7;
        float x1 = ainf[(0*3+p)*128 + b];
        float x2 = ainf[(1*3+p)*128 + b];
        float cosv = (x1*x2) / fmaxf(fabsf(x1)*fabsf(x2), 1e-8f);
        float distv = fabsf(x1 - x2 + 1e-6f);
        long fb = (long)b*FSTRIDE_;
        feat[fb + p*8 + 6] = cosv;
        feat[fb + p*8 + 7] = distv;
        long vb = 24 + (long)p*2721 + 9L*302;
        feat[fb + vb + 0] = cosv;
        feat[fb + vb + 1] = distv;
        feat[fb + vb + 2] = fabsf(x1 - x2);
    }
}

// ------------------------------------------------- MLP layer 1: MFMA split-K v6
__global__ __launch_bounds__(512) void k_mlp1(const float* __restrict__ feat,
        const float* __restrict__ W1, float* __restrict__ hpart){
    __shared__ __align__(16) unsigned short Bh[2][5120];   // 4 k-octets * 160 n * 8
    __shared__ __align__(16) unsigned short Bl[2][5120];
    int tid = threadIdx.x;
    int w = tid >> 6, lane = tid & 63, col = lane & 15, quad = lane >> 4;
    int z = blockIdx.x;
    int t0 = z * KCB_;
    int ns = KST_ - t0; if (ns > KCB_) ns = KCB_;
    long hbase = (long)z * (128*160);
    int mrow = w*16 + col;                       // wave's m-tile row for A-frag

    if (ns <= 0){
        #pragma unroll
        for (int ni = 0; ni < 10; ++ni)
            #pragma unroll
            for (int r = 0; r < 4; ++r)
                hpart[hbase + (long)(w*16 + quad*4 + r)*160 + ni*16 + col] = 0.0f;
        return;
    }

    // B staging assignment: 2560 (k-pair, n) cells, 5 per thread (constant per step)
    int k2a[5], na[5];
    #pragma unroll
    for (int i = 0; i < 5; ++i){
        int p = i*512 + tid;
        k2a[i] = p / 160; na[i] = p - 160*k2a[i];   // k2 in 0..15 (k = 2*k2), n in 0..159
    }

    const float* arow = feat + (long)mrow * FSTRIDE_;
    float af[8];                 // raw A dwords for current/next step
    float bf0[5], bf1[5];        // raw B pair values
    bf16x8 ah, al;               // current A frags
    f32x4 acc[10] = {};

#define LOADA(STEP) do { \
        int ks_ = t0 + (STEP); \
        int kb_ = ks_*32 + quad*8; \
        if (ks_ < 1388){ \
            float4 f0_ = *(const float4*)(arow + kb_); \
            float4 f1_ = *(const float4*)(arow + kb_ + 4); \
            af[0]=f0_.x; af[1]=f0_.y; af[2]=f0_.z; af[3]=f0_.w; \
            af[4]=f1_.x; af[5]=f1_.y; af[6]=f1_.z; af[7]=f1_.w; \
        } else { \
            _Pragma("unroll") \
            for (int j_ = 0; j_ < 8; ++j_){ \
                int k_ = kb_ + j_; \
                af[j_] = (k_ < NFEAT_) ? arow[k_] : 0.0f; \
            } \
        } } while(0)

#define LOADB(STEP) do { \
        int kb_ = (t0 + (STEP))*32; \
        _Pragma("unroll") \
        for (int i_ = 0; i_ < 5; ++i_){ \
            int k_ = kb_ + 2*k2a[i_]; int n_ = na[i_]; \
            bf0[i_] = (k_   < NFEAT_ && n_ < HID_) ? W1[(long)k_*HID_ + n_]     : 0.0f; \
            bf1[i_] = (k_+1 < NFEAT_ && n_ < HID_) ? W1[(long)(k_+1)*HID_ + n_] : 0.0f; \
        } } while(0)

#define CVTA() do { \
        _Pragma("unroll") \
        for (int j_ = 0; j_ < 8; ++j_){ \
            unsigned short h_ = f2bf(af[j_]); \
            unsigned short l_ = f2bf(af[j_] - bf2f(h_)); \
            ah[j_] = (short)h_; al[j_] = (short)l_; \
        } } while(0)

#define WRITEB(BUF) do { \
        _Pragma("unroll") \
        for (int i_ = 0; i_ < 5; ++i_){ \
            int k2_ = k2a[i_]; int n_ = na[i_]; \
            int q_ = k2_ >> 2, off_ = k2_ & 3; \
            unsigned short h0_ = f2bf(bf0[i_]); \
            unsigned short l0_ = f2bf(bf0[i_] - bf2f(h0_)); \
            unsigned short h1_ = f2bf(bf1[i_]); \
            unsigned short l1_ = f2bf(bf1[i_] - bf2f(h1_)); \
            int ui_ = (q_*160 + n_)*4 + off_; \
            ((unsigned*)Bh[BUF])[ui_] = (unsigned)h0_ | ((unsigned)h1_ << 16); \
            ((unsigned*)Bl[BUF])[ui_] = (unsigned)l0_ | ((unsigned)l1_ << 16); \
        } } while(0)

    // prologue: fetch step 0, stage B(0) into buf 0
    LOADB(0);
    LOADA(0);
    WRITEB(0);

    for (int t = 0; t < ns; ++t){
        __syncthreads();                       // B(t) LDS writes visible to all waves
        CVTA();                                // A(t) raw -> frags (waits its vmcnt)
        bool more = (t+1 < ns);
        if (more){ LOADA(t+1); LOADB(t+1); }   // issue next-step global loads early
        int bi = t & 1;
        #pragma unroll
        for (int ni = 0; ni < 10; ++ni){
            bf16x8 bh = *(const bf16x8*)&Bh[bi][(quad*160 + ni*16 + col)*8];
            bf16x8 bl = *(const bf16x8*)&Bl[bi][(quad*160 + ni*16 + col)*8];
            acc[ni] = __builtin_amdgcn_mfma_f32_16x16x32_bf16(ah, bh, acc[ni], 0,0,0);
            acc[ni] = __builtin_amdgcn_mfma_f32_16x16x32_bf16(al, bh, acc[ni], 0,0,0);
            acc[ni] = __builtin_amdgcn_mfma_f32_16x16x32_bf16(ah, bl, acc[ni], 0,0,0);
        }
        if (more) WRITEB((t+1)&1);             // waits B(t+1) vmcnt; other buffer
    }

#undef LOADA
#undef LOADB
#undef CVTA
#undef WRITEB

    #pragma unroll
    for (int ni = 0; ni < 10; ++ni)
        #pragma unroll
        for (int r = 0; r < 4; ++r)
            hpart[hbase + (long)(w*16 + quad*4 + r)*160 + ni*16 + col] = acc[ni][r];
}

// ------------------------------------------------- reduce split-K partials v2
// grid (75, 4): y-chunk sums 64 z's -> 300 blocks. k_final sums the 4 slices.
__global__ void k_red(const float* __restrict__ hpart, float* __restrict__ hpre4){
    int t = blockIdx.x*256 + threadIdx.x;
    if (t >= 128*HID_) return;
    int y = blockIdx.y;
    int b = t / HID_, n = t % HID_;
    float s = 0.0f;
    int z0 = y*64;
    for (int z = z0; z < z0+64; ++z)
        s += hpart[(long)z*(128*160) + (long)b*160 + n];
    hpre4[(long)y*(128*HID_) + t] = s;
}

// ------------------------------------------------- tanh + layer2 + log_softmax v2
// 128 blocks x 64 lanes (was 1 block x 128 serial threads = pure latency tail).
// Lane-parallel over n with shuffle reduce; FP sum order changes (within tol).
__global__ void k_final(const float* __restrict__ hpre4, const float* __restrict__ b1,
        const float* __restrict__ W2, const float* __restrict__ b2,
        float* __restrict__ out){
    int b = blockIdx.x;
    int lane = threadIdx.x;                    // 64
    float z0 = 0.0f, z1 = 0.0f;
    for (int n = lane; n < HID_; n += 64){
        int idx = b*HID_ + n;
        float hp = hpre4[idx] + hpre4[19200 + idx] + hpre4[38400 + idx] + hpre4[57600 + idx];
        float hv = fast_tanh(hp + b1[n]);
        z0 = fmaf(hv, W2[n*2+0], z0);
        z1 = fmaf(hv, W2[n*2+1], z1);
    }
    for (int m = 1; m < 64; m <<= 1){
        z0 += __shfl_xor(z0, m, 64);
        z1 += __shfl_xor(z1, m, 64);
    }
    if (lane == 0){
        z0 += b2[0]; z1 += b2[1];
        float m = fmaxf(z0, z1);
        float lse = m + logf(expf(z0-m) + expf(z1-m));
        out[b*2+0] = z0 - lse;
        out[b*2+1] = z1 - lse;
    }
}

extern "C" void kernel_launch(void* const* d_in, const int* in_sizes, int n_in,
                              void* d_out, int out_size, void* d_ws, size_t ws_size,
                              hipStream_t stream){
    const int*   sa  = (const int*)d_in[0];
    const int*   sb  = (const int*)d_in[1];
    const float* emb = (const float*)d_in[2];
    const float* hw1 = (const float*)d_in[3];
    const float* hb1 = (const float*)d_in[4];
    const float* pw1 = (const float*)d_in[5];
    const float* pb1 = (const float*)d_in[6];
    const float* hw2 = (const float*)d_in[7];
    const float* hb2 = (const float*)d_in[8];
    const float* pw2 = (const float*)d_in[9];
    const float* pb2 = (const float*)d_in[10];
    const float* hw3 = (const float*)d_in[11];
    const float* hb3 = (const float*)d_in[12];
    const float* pw3 = (const float*)d_in[13];
    const float* pb3 = (const float*)d_in[14];
    const float* W1  = (const float*)d_in[15];
    const float* b1  = (const float*)d_in[16];
    const float* W2  = (const float*)d_in[17];
    const float* b2  = (const float*)d_in[18];
    float* out = (float*)d_out;

    float* ws    = (float*)d_ws;
    float* S     = ws;                       // 300*16384      = 4,915,200
    float* APOOL = S + 4915200;              // 2*3*3*128*300  =   691,200
    float* AINF  = APOOL + 691200;           // 2*3*128        =       768
    float* PPOOL = AINF + 768;               // 2*3*2*128*6000 = 9,216,000
    float* FEAT  = PPOOL + 9216000;          // 128*44428      = 5,686,784 (padded rows)
    float* HPRE  = FEAT + 5686784;           // 4*128*150      =    76,800
    // SBFK/WBF DEDICATED (no PPOOL overlay) so k_conv's hconv and pdim/inf
    // parts are truly independent and can share one launch:
    unsigned short* SBFK = (unsigned short*)(HPRE + 76800);   // 10*16448*32 ushorts
    unsigned short* WBF  = SBFK + 10*NROWS_*32;               // 614,400 ushorts
    // HPART (256*128*160 = 5,242,880 floats) overlays S..APOOL (dead by mlp1)
    float* HPART = ws;

    k_prep<<<2977, 256, 0, stream>>>(sa, sb, emb, hw1, hw2, hw3, S, SBFK, WBF);
    k_conv<<<7792, 256, 0, stream>>>(SBFK, WBF, hb1, hb2, hb3, APOOL,
                                     S, pw1,pb1, pw2,pb2, pw3,pb3, PPOOL, AINF);
    k_feat<<<1634, 256, 0, stream>>>(APOOL, AINF, PPOOL, FEAT);
    k_mlp1<<<dim3(ZB_), 512, 0, stream>>>(FEAT, W1, HPART);
    k_red<<<dim3(75, 4), 256, 0, stream>>>(HPART, HPRE);
    k_final<<<128, 64, 0, stream>>>(HPRE, b1, W2, b2, out);
}